// Round 10
// baseline (3668.895 us; speedup 1.0000x reference)
//
#include <hip/hip_runtime.h>
#include <cstdint>
#include <cstddef>

#define EMB 300
#define EMB2 600
#define NLAYER 5
#define SLD 304     // state/agg row stride (300 -> 304, 1216B rows)
#define KP1 320     // padded K for GEMM1 (300 -> 320, zeros injected in-register)
#define NP1 640     // GEMM1 out width / GEMM2 K (600 -> 640)
#define NP2 384     // 300 -> 3*128 col-tile cover
#define SCAN_B 256
#define W1SZ ((size_t)NP1 * KP1 * 2)     // 409600 B, 256-aligned
#define W2SZ ((size_t)NP2 * NP1 * 2)     // 491520 B, 256-aligned
#define LSTRIDE (2 * W1SZ + 2 * W2SZ)    // per-layer weight-plane block

typedef short bf16x8 __attribute__((ext_vector_type(8)));
typedef float f32x4 __attribute__((ext_vector_type(4)));
typedef unsigned int u32x4 __attribute__((ext_vector_type(4)));
typedef unsigned short ushort_t;
typedef unsigned int uint_t;

static inline int cdiv(int a, int b) { return (a + b - 1) / b; }

__device__ inline ushort_t f2bf(float v) {
    unsigned u = __float_as_uint(v);
    u += 0x7fffu + ((u >> 16) & 1u);
    return (ushort_t)(u >> 16);
}
__device__ inline float bf2f(ushort_t h) { return __uint_as_float(((unsigned)h) << 16); }

// pack fp32 -> interleaved word: hi bf16 in [15:0], lo bf16 in [31:16]
__device__ inline uint_t packbf(float v) {
    ushort_t h = f2bf(v);
    ushort_t l = f2bf(v - bf2f(h));
    return (uint_t)h | ((uint_t)l << 16);
}
__device__ inline u32x4 pack4(f32x4 v) {
    u32x4 w;
    #pragma unroll
    for (int j = 0; j < 4; ++j) w[j] = packbf(v[j]);
    return w;
}

__device__ inline f32x4 bnrelu4(f32x4 v, f32x4 s, f32x4 h, bool use_bn) {
    if (!use_bn) return v;
    f32x4 r;
    #pragma unroll
    for (int j = 0; j < 4; ++j) r[j] = fmaxf(fmaf(v[j], s[j], h[j]), 0.f);
    return r;
}

// ---------------- zero fill ----------------
__global__ __launch_bounds__(256) void zero_kernel(float* __restrict__ p, size_t n)
{
    size_t i = (size_t)blockIdx.x * blockDim.x + threadIdx.x;
    size_t stride = (size_t)gridDim.x * blockDim.x;
    for (; i < n; i += stride) p[i] = 0.f;
}
static inline void launch_zero(float* p, size_t n, hipStream_t s)
{
    int g = (int)((n + 255) / 256);
    if (g > 2048) g = 2048;
    zero_kernel<<<g, 256, 0, s>>>(p, n);
}
__global__ __launch_bounds__(256) void izero_kernel(int* __restrict__ p, int n)
{
    int i = blockIdx.x * 256 + threadIdx.x;
    if (i < n) p[i] = 0;
}

// ---------------- embed (ld = SLD) ----------------
__global__ __launch_bounds__(256) void embed_kernel(
    const int* __restrict__ x, const float* __restrict__ a1,
    const float* __restrict__ a2, float* __restrict__ h, int N)
{
    int idx = blockIdx.x * blockDim.x + threadIdx.x;
    if (idx >= N * EMB) return;
    int row = idx / EMB, col = idx % EMB;
    h[(size_t)row * SLD + col] = a1[x[2 * row] * EMB + col] + a2[x[2 * row + 1] * EMB + col];
}

// ---------------- CSR build ----------------
__global__ __launch_bounds__(256) void count_kernel(
    const int* __restrict__ dst, int* __restrict__ cnt, int E)
{
    int e = blockIdx.x * 256 + threadIdx.x;
    if (e < E) atomicAdd(&cnt[dst[e]], 1);
}

__global__ __launch_bounds__(SCAN_B) void scan_block_kernel(
    const int* __restrict__ in, int* __restrict__ out, int* __restrict__ bsum, int n)
{
    __shared__ int s[SCAN_B];
    int t = threadIdx.x, i = blockIdx.x * SCAN_B + t;
    int v = (i < n) ? in[i] : 0;
    s[t] = v; __syncthreads();
    for (int o = 1; o < SCAN_B; o <<= 1) {
        int xv = (t >= o) ? s[t - o] : 0;
        __syncthreads();
        s[t] += xv;
        __syncthreads();
    }
    if (i < n) out[i] = s[t] - v;
    if (t == SCAN_B - 1) bsum[blockIdx.x] = s[t];
}

__global__ __launch_bounds__(512) void scan_partials_kernel(
    const int* __restrict__ bsum, int* __restrict__ bbase, int nb)
{
    __shared__ int s[512];
    int t = threadIdx.x;
    int v = (t < nb) ? bsum[t] : 0;
    s[t] = v; __syncthreads();
    for (int o = 1; o < 512; o <<= 1) {
        int xv = (t >= o) ? s[t - o] : 0;
        __syncthreads();
        s[t] += xv;
        __syncthreads();
    }
    if (t < nb) bbase[t] = s[t] - v;
}

__global__ __launch_bounds__(256) void scan_add_kernel(
    int* __restrict__ off, const int* __restrict__ bbase, int n, int total)
{
    int i = blockIdx.x * 256 + threadIdx.x;
    if (i < n) off[i] += bbase[i / SCAN_B];
    if (i == 0) off[n] = total;
}

__global__ __launch_bounds__(256) void fill_kernel(
    const int* __restrict__ dst, const int* __restrict__ off,
    int* __restrict__ cursor, int* __restrict__ eid, int E)
{
    int e = blockIdx.x * 256 + threadIdx.x;
    if (e >= E) return;
    int d = dst[e];
    int p = atomicAdd(&cursor[d], 1);
    eid[off[d] + p] = e;
}

// ---------------- fragment range offsets (frag_batch sorted) ----------------
__global__ __launch_bounds__(256) void poff_kernel(
    const int* __restrict__ fb, int* __restrict__ poff, int N, int P)
{
    int i = blockIdx.x * 256 + threadIdx.x;
    if (i >= N) return;
    int b = fb[i];
    if (i == 0) { for (int q = 0; q <= b; ++q) poff[q] = 0; }
    else { int a = fb[i - 1]; for (int q = a + 1; q <= b; ++q) poff[q] = i; }
    if (i == N - 1) { for (int q = b + 1; q <= P; ++q) poff[q] = N; }
}

// ---------------- edge-emb combos ----------------
__global__ __launch_bounds__(256) void e12all_kernel(
    const float* __restrict__ ge1, const float* __restrict__ ge2,
    float* __restrict__ E12all)
{
    int idx = blockIdx.x * 256 + threadIdx.x;
    if (idx >= NLAYER * 18 * EMB) return;
    int l = idx / (18 * EMB);
    int rem = idx - l * 18 * EMB;
    int cmb = rem / EMB, c = rem - cmb * EMB;
    E12all[idx] = ge1[(size_t)l * 6 * EMB + (cmb / 3) * EMB + c]
                + ge2[(size_t)l * 3 * EMB + (cmb % 3) * EMB + c];
}

// ---------------- BN finalize ----------------
__global__ __launch_bounds__(256) void bn_finalize_kernel(
    const float* __restrict__ stats, const float* __restrict__ g,
    const float* __restrict__ b, float* __restrict__ scale,
    float* __restrict__ shift, float invN)
{
    int c = blockIdx.x * 256 + threadIdx.x;
    if (c >= EMB) return;
    float mu = stats[c] * invN;
    float var = fmaf(-mu, mu, stats[EMB + c] * invN);
    float s = rsqrtf(var + 1e-5f) * g[c];
    scale[c] = s;
    shift[c] = fmaf(-mu, s, b[c]);
}

// ---------------- GIN gather (unroll-2): state(f32, ld SLD) -> packed agg (u32, ld SLD) ----------------
__global__ __launch_bounds__(256) void gin_gather_il(
    const float* __restrict__ hin, const float* __restrict__ scale,
    const float* __restrict__ shift, int use_bn,
    const int* __restrict__ off, const int* __restrict__ eid,
    const int* __restrict__ src, const int* __restrict__ ea,
    const float* __restrict__ E12, uint_t* __restrict__ Yil, int N)
{
    int node = (blockIdx.x * blockDim.x + threadIdx.x) >> 6;
    int lane = threadIdx.x & 63;
    if (node >= N) return;
    const bool tl = lane < 11;            // cols 256..299
    const int c0 = lane * 4, c1 = 256 + lane * 4;
    f32x4 sc0 = {1,1,1,1}, sh0 = {0,0,0,0}, sc1 = {1,1,1,1}, sh1 = {0,0,0,0};
    if (use_bn) {
        sc0 = *(const f32x4*)(scale + c0); sh0 = *(const f32x4*)(shift + c0);
        if (tl) { sc1 = *(const f32x4*)(scale + c1); sh1 = *(const f32x4*)(shift + c1); }
    }
    const float* selfrow = E12 + 12 * EMB;   // (a0=4, a1=0)
    f32x4 a0, a1 = {0,0,0,0};
    {
        const float* hr = hin + (size_t)node * SLD;
        a0 = bnrelu4(*(const f32x4*)(hr + c0), sc0, sh0, use_bn) + *(const f32x4*)(selfrow + c0);
        if (tl) a1 = bnrelu4(*(const f32x4*)(hr + c1), sc1, sh1, use_bn) + *(const f32x4*)(selfrow + c1);
    }
    f32x4 b0 = {0,0,0,0}, b1 = {0,0,0,0};   // second accumulator (unroll-2)

    int j0 = off[node], j1 = off[node + 1];
    int sA = 0, cA = 0, sB = 0, cB = 0;
    if (j0 < j1)     { int e = eid[j0];     sA = src[e]; cA = ea[2 * e] * 3 + ea[2 * e + 1]; }
    if (j0 + 1 < j1) { int e = eid[j0 + 1]; sB = src[e]; cB = ea[2 * e] * 3 + ea[2 * e + 1]; }
    int j = j0;
    for (; j + 1 < j1; j += 2) {
        int snA = 0, cnA = 0, snB = 0, cnB = 0;
        if (j + 2 < j1) { int e = eid[j + 2]; snA = src[e]; cnA = ea[2 * e] * 3 + ea[2 * e + 1]; }
        if (j + 3 < j1) { int e = eid[j + 3]; snB = src[e]; cnB = ea[2 * e] * 3 + ea[2 * e + 1]; }
        const float* hA = hin + (size_t)sA * SLD;
        const float* hB = hin + (size_t)sB * SLD;
        const float* eA = E12 + (size_t)cA * EMB;
        const float* eB = E12 + (size_t)cB * EMB;
        // two independent row streams -> 2x memory-level parallelism
        a0 += bnrelu4(*(const f32x4*)(hA + c0), sc0, sh0, use_bn) + *(const f32x4*)(eA + c0);
        b0 += bnrelu4(*(const f32x4*)(hB + c0), sc0, sh0, use_bn) + *(const f32x4*)(eB + c0);
        if (tl) {
            a1 += bnrelu4(*(const f32x4*)(hA + c1), sc1, sh1, use_bn) + *(const f32x4*)(eA + c1);
            b1 += bnrelu4(*(const f32x4*)(hB + c1), sc1, sh1, use_bn) + *(const f32x4*)(eB + c1);
        }
        sA = snA; cA = cnA; sB = snB; cB = cnB;
    }
    if (j < j1) {   // odd leftover (header already in sA/cA)
        const float* hA = hin + (size_t)sA * SLD;
        const float* eA = E12 + (size_t)cA * EMB;
        a0 += bnrelu4(*(const f32x4*)(hA + c0), sc0, sh0, use_bn) + *(const f32x4*)(eA + c0);
        if (tl) a1 += bnrelu4(*(const f32x4*)(hA + c1), sc1, sh1, use_bn) + *(const f32x4*)(eA + c1);
    }
    a0 += b0;
    if (tl) a1 += b1;

    uint_t* pw = Yil + (size_t)node * SLD;
    __builtin_nontemporal_store(pack4(a0), (u32x4*)(pw + c0));
    if (tl) __builtin_nontemporal_store(pack4(a1), (u32x4*)(pw + c1));
}

// ---------------- bf16x3 MFMA GEMM: interleaved u32 A, planar B ----------------
// out_mode: 0 = fp32 masked (+stats); 1 = packed full-tile (zero pad); 2 = both.
__global__ __launch_bounds__(256) void gemm_il(
    const uint_t* __restrict__ Ail, int lda, int Mvalid, int Kvalid,
    const ushort_t* __restrict__ Bhi, const ushort_t* __restrict__ Blo, int ldb,
    const float* __restrict__ bias, int Kpad, int Nvalid,
    float* __restrict__ Cf, int ldcf,
    uint_t* __restrict__ Cil, int ldcs,
    int relu, int out_mode, float* __restrict__ stats)
{
    __shared__ ushort_t As[2][128][40];   // 40-pad: frag b128 reads bank-balanced
    __shared__ ushort_t Bs[2][128][40];
    __shared__ float cred[128][2];
    const int tid = threadIdx.x;
    const int lane = tid & 63, wid = tid >> 6;
    const int wr = wid >> 1, wc = wid & 1;
    const int lr = lane & 15, ko = (lane >> 4) * 8;

    // bijective XCD swizzle (m204)
    int gx = gridDim.x;
    int nwg = gx * gridDim.y;
    int flat = blockIdx.y * gx + blockIdx.x;
    if (nwg >= 8) {
        int q = nwg >> 3, r = nwg & 7, xc = flat & 7, s = flat >> 3;
        flat = (xc < r ? xc * (q + 1) : r * (q + 1) + (xc - r) * q) + s;
    }
    const int row0 = (flat / gx) * 128, col0 = (flat % gx) * 128;

    const int srow = tid >> 1;
    const int sc = (tid & 1) * 16;

    const bool arow_ok = (row0 + srow) < Mvalid;
    const uint_t* pA = Ail + (size_t)(row0 + srow) * lda + sc;
    const ushort_t* pBhi = Bhi + (size_t)(col0 + srow) * ldb + sc;
    const ushort_t* pBlo = Blo + (size_t)(col0 + srow) * ldb + sc;
    const u32x4 z4 = {0u, 0u, 0u, 0u};

    f32x4 acc[4][4] = {};
    u32x4 LA[4];
    bf16x8 rB0, rB1, rB2, rB3;

    #pragma unroll
    for (int q = 0; q < 4; ++q) {
        int kc = sc + q * 4;
        LA[q] = (arow_ok && kc < Kvalid) ? *(const u32x4*)(pA + q * 4) : z4;
    }
    rB0 = *(const bf16x8*)(pBhi);     rB1 = *(const bf16x8*)(pBhi + 8);
    rB2 = *(const bf16x8*)(pBlo);     rB3 = *(const bf16x8*)(pBlo + 8);

    for (int k0 = 0; k0 < Kpad; k0 += 32) {
        uint_t hw[8], lw[8];
        #pragma unroll
        for (int i = 0; i < 8; ++i) {
            uint_t w0 = LA[(2 * i) >> 2][(2 * i) & 3];
            uint_t w1 = LA[(2 * i + 1) >> 2][(2 * i + 1) & 3];
            hw[i] = (w0 & 0xFFFFu) | (w1 << 16);
            lw[i] = (w0 >> 16) | (w1 & 0xFFFF0000u);
        }
        *(u32x4*)&As[0][srow][sc]     = (u32x4){hw[0], hw[1], hw[2], hw[3]};
        *(u32x4*)&As[0][srow][sc + 8] = (u32x4){hw[4], hw[5], hw[6], hw[7]};
        *(u32x4*)&As[1][srow][sc]     = (u32x4){lw[0], lw[1], lw[2], lw[3]};
        *(u32x4*)&As[1][srow][sc + 8] = (u32x4){lw[4], lw[5], lw[6], lw[7]};
        *(bf16x8*)&Bs[0][srow][sc]     = rB0;
        *(bf16x8*)&Bs[0][srow][sc + 8] = rB1;
        *(bf16x8*)&Bs[1][srow][sc]     = rB2;
        *(bf16x8*)&Bs[1][srow][sc + 8] = rB3;
        __syncthreads();
        if (k0 + 32 < Kpad) {
            int kn = k0 + 32;
            #pragma unroll
            for (int q = 0; q < 4; ++q) {
                int kc = kn + sc + q * 4;
                LA[q] = (arow_ok && kc < Kvalid) ? *(const u32x4*)(pA + kn + q * 4) : z4;
            }
            rB0 = *(const bf16x8*)(pBhi + kn);     rB1 = *(const bf16x8*)(pBhi + kn + 8);
            rB2 = *(const bf16x8*)(pBlo + kn);     rB3 = *(const bf16x8*)(pBlo + kn + 8);
        }
        bf16x8 afh[4], afl[4], bfh[4], bfl[4];
        #pragma unroll
        for (int f = 0; f < 4; ++f) {
            int ar = wr * 64 + f * 16 + lr;
            afh[f] = *(const bf16x8*)&As[0][ar][ko];
            afl[f] = *(const bf16x8*)&As[1][ar][ko];
            int bc = wc * 64 + f * 16 + lr;
            bfh[f] = *(const bf16x8*)&Bs[0][bc][ko];
            bfl[f] = *(const bf16x8*)&Bs[1][bc][ko];
        }
        #pragma unroll
        for (int f = 0; f < 4; ++f)
            #pragma unroll
            for (int g = 0; g < 4; ++g) {
                acc[f][g] = __builtin_amdgcn_mfma_f32_16x16x32_bf16(afh[f], bfh[g], acc[f][g], 0, 0, 0);
                acc[f][g] = __builtin_amdgcn_mfma_f32_16x16x32_bf16(afh[f], bfl[g], acc[f][g], 0, 0, 0);
                acc[f][g] = __builtin_amdgcn_mfma_f32_16x16x32_bf16(afl[f], bfh[g], acc[f][g], 0, 0, 0);
            }
        __syncthreads();
    }

    // epilogue: C/D mapping col=lane&15, row=(lane>>4)*4+reg  [m89-verified]
    float ts[4] = {0.f, 0.f, 0.f, 0.f}, ts2[4] = {0.f, 0.f, 0.f, 0.f};
    #pragma unroll
    for (int f = 0; f < 4; ++f) {
        int grb = row0 + wr * 64 + f * 16 + (lane >> 4) * 4;
        #pragma unroll
        for (int g = 0; g < 4; ++g) {
            int gc = col0 + wc * 64 + g * 16 + lr;
            float bv = (gc < Nvalid) ? bias[gc] : 0.f;
            #pragma unroll
            for (int j = 0; j < 4; ++j) {
                int gr = grb + j;
                float v = acc[f][g][j] + bv;
                if (relu) v = fmaxf(v, 0.f);
                if (out_mode != 1) {              // fp32 masked (+stats)
                    if (gr < Mvalid && gc < Nvalid) {
                        Cf[(size_t)gr * ldcf + gc] = v;
                        if (stats) {
                            ts[g] += v;
                            ts2[g] = fmaf(v, v, ts2[g]);
                        }
                    }
                }
                if (out_mode >= 1) {              // packed full-tile, zero pad
                    float vp = (gc < Nvalid) ? v : 0.f;
                    Cil[(size_t)gr * ldcs + gc] = packbf(vp);
                }
            }
        }
    }
    if (stats && out_mode != 1) {
        ((float*)cred)[tid] = 0.f;
        __syncthreads();
        #pragma unroll
        for (int g = 0; g < 4; ++g) {
            int cidx = wc * 64 + g * 16 + lr;
            atomicAdd(&cred[cidx][0], ts[g]);
            atomicAdd(&cred[cidx][1], ts2[g]);
        }
        __syncthreads();
        if (tid < 128) {
            int gc = col0 + tid;
            if (gc < Nvalid) {
                atomicAdd(&stats[gc], cred[tid][0]);
                atomicAdd(&stats[EMB + gc], cred[tid][1]);
            }
        }
    }
}

// ---------------- batched GIN weight split (all 5 layers, one launch) ----------------
// Plane blocks are carved contiguously: per layer [w1hi|w1lo|w2hi|w2lo], stride LSTRIDE.
__global__ __launch_bounds__(256) void wsplit_gin_kernel(
    const float* __restrict__ w1, const float* __restrict__ w2, char* __restrict__ base)
{
    const int perLayer = NP1 * KP1 + NP2 * NP1;
    int idx = blockIdx.x * 256 + threadIdx.x;
    if (idx >= NLAYER * perLayer) return;
    int l = idx / perLayer;
    int r = idx - l * perLayer;
    char* lb = base + (size_t)l * LSTRIDE;
    if (r < NP1 * KP1) {                  // w1t: [NP1][KP1] from w1[l][EMB][EMB2]
        int n = r / KP1, k = r - n * KP1;
        float v = (n < EMB2 && k < EMB) ? w1[(size_t)l * EMB * EMB2 + (size_t)k * EMB2 + n] : 0.f;
        ushort_t h = f2bf(v);
        ((ushort_t*)lb)[r] = h;
        ((ushort_t*)(lb + W1SZ))[r] = f2bf(v - bf2f(h));
    } else {                              // w2t: [NP2][NP1] from w2[l][EMB2][EMB]
        r -= NP1 * KP1;
        int n = r / NP1, k = r - n * NP1;
        float v = (n < EMB && k < EMB2) ? w2[(size_t)l * EMB2 * EMB + (size_t)k * EMB + n] : 0.f;
        ushort_t h = f2bf(v);
        ((ushort_t*)(lb + 2 * W1SZ))[r] = h;
        ((ushort_t*)(lb + 2 * W1SZ + W2SZ))[r] = f2bf(v - bf2f(h));
    }
}

// ---------------- weight transpose + split (P-phase, planar hi/lo) ----------------
__global__ __launch_bounds__(256) void wsplit_kernel(
    const float* __restrict__ W, int K, int Nc,
    ushort_t* __restrict__ hi, ushort_t* __restrict__ lo, int Kpad, int Npad)
{
    int idx = blockIdx.x * 256 + threadIdx.x;
    if (idx >= Npad * Kpad) return;
    int n = idx / Kpad, k = idx - n * Kpad;
    float v = (n < Nc && k < K) ? W[(size_t)k * Nc + n] : 0.f;
    ushort_t h = f2bf(v);
    hi[idx] = h;
    lo[idx] = f2bf(v - bf2f(h));
}

// ---------------- pool: contiguous ranges + analytic BN -> PACKED pooled (ld KP1) ----------------
__global__ __launch_bounds__(256) void pool_gather_il(
    const float* __restrict__ hin, const float* __restrict__ scale,
    const float* __restrict__ shift, const int* __restrict__ poff,
    uint_t* __restrict__ pooledIl, int P)
{
    int p = (blockIdx.x * blockDim.x + threadIdx.x) >> 6;
    int lane = threadIdx.x & 63;
    if (p >= P) return;
    const bool tl = lane < 11;
    const int c0 = lane * 4, c1 = 256 + lane * 4;
    int r0 = poff[p], r1 = poff[p + 1];
    f32x4 s0 = {0,0,0,0}, s1 = {0,0,0,0};
    for (int r = r0; r < r1; ++r) {
        const float* hr = hin + (size_t)r * SLD;
        s0 += *(const f32x4*)(hr + c0);
        if (tl) s1 += *(const f32x4*)(hr + c1);
    }
    float cntf = (float)(r1 - r0);
    float inv = 1.f / fmaxf(cntf, 1.f);
    f32x4 sc0 = *(const f32x4*)(scale + c0), sh0 = *(const f32x4*)(shift + c0);
    f32x4 o0;
    #pragma unroll
    for (int j = 0; j < 4; ++j) o0[j] = fmaf(s0[j], sc0[j], cntf * sh0[j]) * inv;
    uint_t* pr = pooledIl + (size_t)p * KP1;
    *(u32x4*)(pr + c0) = pack4(o0);
    if (tl) {
        f32x4 sc1 = *(const f32x4*)(scale + c1), sh1 = *(const f32x4*)(shift + c1);
        f32x4 o1;
        #pragma unroll
        for (int j = 0; j < 4; ++j) o1[j] = fmaf(s1[j], sc1[j], cntf * sh1[j]) * inv;
        *(u32x4*)(pr + c1) = pack4(o1);   // cols 300..319 masked by Kvalid in gemm
    }
}

// ---------------- row L2 normalize ----------------
__global__ __launch_bounds__(256) void normalize_rows_kernel(
    const float* __restrict__ X, float* __restrict__ Y, int M)
{
    int wv = (blockIdx.x * blockDim.x + threadIdx.x) >> 6;
    int lane = threadIdx.x & 63;
    if (wv >= M) return;
    const float* x = X + (size_t)wv * EMB;
    float ss = 0.f;
    for (int c = lane; c < EMB; c += 64) { float v = x[c]; ss = fmaf(v, v, ss); }
    #pragma unroll
    for (int o = 32; o > 0; o >>= 1) ss += __shfl_xor(ss, o, 64);
    float inv = 1.f / fmaxf(sqrtf(ss), 1e-12f);
    float* y = Y + (size_t)wv * EMB;
    for (int c = lane; c < EMB; c += 64) y[c] = x[c] * inv;
}

// ---------------- GCN ----------------
__global__ __launch_bounds__(256) void deg_kernel(
    const int* __restrict__ fei, float* __restrict__ deg, int FE)
{
    int i = blockIdx.x * blockDim.x + threadIdx.x;
    if (i < 2 * FE) atomicAdd(&deg[fei[i]], 1.f);
}

__global__ __launch_bounds__(256) void gcn_scatter_kernel(
    const float* __restrict__ xw, const int* __restrict__ fei,
    const int* __restrict__ dea, const float* __restrict__ e1,
    const float* __restrict__ e2, const float* __restrict__ deg,
    float* __restrict__ pred, int FE)
{
    int i = (blockIdx.x * blockDim.x + threadIdx.x) >> 6;
    int lane = threadIdx.x & 63;
    if (i >= 2 * FE) return;
    int u = fei[i];
    int v = (i < FE) ? fei[i + FE] : fei[i - FE];
    int er = (i < FE) ? i : i - FE;
    int a0 = dea[2 * er], a1 = dea[2 * er + 1];
    float du = deg[u], dv = deg[v];
    float su = du > 0.f ? rsqrtf(fmaxf(du, 1.f)) : 0.f;
    float sv = dv > 0.f ? rsqrtf(fmaxf(dv, 1.f)) : 0.f;
    float nr = su * sv;
    const float* xu = xw + (size_t)u * EMB;
    const float* t1 = e1 + (size_t)a0 * EMB;
    const float* t2 = e2 + (size_t)a1 * EMB;
    float* pv = pred + (size_t)v * EMB;
    for (int c = lane; c < EMB; c += 64)
        atomicAdd(&pv[c], nr * (xu[c] + t1[c] + t2[c]));
}

// ---------------- classifier ----------------
__global__ __launch_bounds__(256) void classifier_kernel(
    const float* __restrict__ f0, const float* __restrict__ f1,
    const float* __restrict__ w, const float* __restrict__ b,
    float* __restrict__ out, int P)
{
    int q = (blockIdx.x * blockDim.x + threadIdx.x) >> 6;
    int lane = threadIdx.x & 63;
    if (q >= 2 * P) return;
    int i = (q < P) ? q : q - P;
    int j = (q < P) ? i : (i == 0 ? P - 1 : i - 1);
    const float* a = f0 + (size_t)i * EMB;
    const float* c = f1 + (size_t)j * EMB;
    float s = 0.f;
    for (int k = lane; k < EMB; k += 64) s = fmaf(fmaxf(a[k], c[k]), w[k], s);
    #pragma unroll
    for (int o = 32; o > 0; o >>= 1) s += __shfl_xor(s, o, 64);
    if (lane == 0) out[q] = s + b[0];
}

extern "C" void kernel_launch(void* const* d_in, const int* in_sizes, int n_in,
                              void* d_out, int out_size, void* d_ws, size_t ws_size,
                              hipStream_t stream)
{
    const int*   x     = (const int*)d_in[0];
    const int*   ei    = (const int*)d_in[1];
    const int*   ea    = (const int*)d_in[2];
    const int*   fb    = (const int*)d_in[3];
    const int*   fei   = (const int*)d_in[4];
    const int*   dea   = (const int*)d_in[5];
    const float* atom1 = (const float*)d_in[7];
    const float* atom2 = (const float*)d_in[8];
    const float* ge1   = (const float*)d_in[9];
    const float* ge2   = (const float*)d_in[10];
    const float* w1    = (const float*)d_in[11];
    const float* b1    = (const float*)d_in[12];
    const float* w2    = (const float*)d_in[13];
    const float* b2    = (const float*)d_in[14];
    const float* bng   = (const float*)d_in[15];
    const float* bnb   = (const float*)d_in[16];
    const float* pw1   = (const float*)d_in[17];
    const float* pb1   = (const float*)d_in[18];
    const float* pw2   = (const float*)d_in[19];
    const float* pb2   = (const float*)d_in[20];
    const float* gw    = (const float*)d_in[21];
    const float* gb    = (const float*)d_in[22];
    const float* gcne1 = (const float*)d_in[23];
    const float* gcne2 = (const float*)d_in[24];
    const float* clw   = (const float*)d_in[25];
    const float* clb   = (const float*)d_in[26];
    (void)n_in; (void)ws_size;

    const int N  = in_sizes[0] / 2;
    const int E  = in_sizes[1] / 2;
    const int FE = in_sizes[4] / 2;
    const int P  = out_size / 2;
    const int Mfull = cdiv(N, 128) * 128;
    const int PM = cdiv(P, 128) * 128;
    float* outF = (float*)d_out;

    // ---- workspace carve: TWO ping-pong buffers + small stuff (~257 MB) ----
    char* wp = (char*)d_ws;
    auto carve = [&](size_t bytes) -> char* {
        char* r = wp;
        wp += (bytes + 255) & ~(size_t)255;
        return r;
    };
    const size_t bufElems = (size_t)Mfull * SLD;      // 4B each
    char* bufA = carve(bufElems * 4);
    char* bufB = carve(bufElems * 4);
    float* statsAll = (float*)carve((size_t)NLAYER * 2 * EMB * 4);
    float* scaleAll = (float*)carve((size_t)NLAYER * EMB * 4);
    float* shiftAll = (float*)carve((size_t)NLAYER * EMB * 4);
    float* E12all   = (float*)carve((size_t)NLAYER * 18 * EMB * 4);
    float* deg      = (float*)carve((size_t)P * 4);
    int* poff    = (int*)carve((size_t)(P + 1) * 4);
    int* cnt_i   = (int*)carve((size_t)N * 4);
    int* csr_off = (int*)carve((size_t)(N + 1) * 4);
    int* cursor  = (int*)carve((size_t)N * 4);
    int* csr_eid = (int*)carve((size_t)E * 4);
    int* bsum    = (int*)carve(512 * 4);
    int* bbase   = (int*)carve(512 * 4);
    // GIN weight planes: contiguous [w1hi|w1lo|w2hi|w2lo] per layer (all sizes 256-aligned)
    char* wplanes = carve((size_t)NLAYER * LSTRIDE);
    ushort_t* w1t_hi[NLAYER]; ushort_t* w1t_lo[NLAYER];
    ushort_t* w2t_hi[NLAYER]; ushort_t* w2t_lo[NLAYER];
    for (int l = 0; l < NLAYER; ++l) {
        char* lb = wplanes + (size_t)l * LSTRIDE;
        w1t_hi[l] = (ushort_t*)lb;
        w1t_lo[l] = (ushort_t*)(lb + W1SZ);
        w2t_hi[l] = (ushort_t*)(lb + 2 * W1SZ);
        w2t_lo[l] = (ushort_t*)(lb + 2 * W1SZ + W2SZ);
    }
    // P-phase weights: pw1t [NP2][KP1]; pw2t,gwt [NP2][NP2]
    ushort_t* pw1t_hi = (ushort_t*)carve((size_t)NP2 * KP1 * 2);
    ushort_t* pw1t_lo = (ushort_t*)carve((size_t)NP2 * KP1 * 2);
    ushort_t* pw2t_hi = (ushort_t*)carve((size_t)NP2 * NP2 * 2);
    ushort_t* pw2t_lo = (ushort_t*)carve((size_t)NP2 * NP2 * 2);
    ushort_t* gwt_hi  = (ushort_t*)carve((size_t)NP2 * NP2 * 2);
    ushort_t* gwt_lo  = (ushort_t*)carve((size_t)NP2 * NP2 * 2);

    // chunking: hidden scratch [CH][NP1] u32 lives in the DEAD ping buffer
    int chCap = (int)((bufElems * 4) / ((size_t)NP1 * 4));
    chCap &= ~127;
    int nChunks = cdiv(Mfull, chCap);
    int CH = cdiv(Mfull / 128, nChunks) * 128;

    const int gElemsN = cdiv(N * EMB, 256);
    const int NB = cdiv(N, SCAN_B);

    // ---- one-time per call ----
    izero_kernel<<<cdiv(N, 256), 256, 0, stream>>>(cnt_i, N);
    count_kernel<<<cdiv(E, 256), 256, 0, stream>>>(ei + E, cnt_i, E);
    scan_block_kernel<<<NB, SCAN_B, 0, stream>>>(cnt_i, csr_off, bsum, N);
    scan_partials_kernel<<<1, 512, 0, stream>>>(bsum, bbase, NB);
    scan_add_kernel<<<cdiv(N, 256), 256, 0, stream>>>(csr_off, bbase, N, E);
    izero_kernel<<<cdiv(N, 256), 256, 0, stream>>>(cursor, N);
    fill_kernel<<<cdiv(E, 256), 256, 0, stream>>>(ei + E, csr_off, cursor, csr_eid, E);
    poff_kernel<<<cdiv(N, 256), 256, 0, stream>>>(fb, poff, N, P);
    e12all_kernel<<<cdiv(NLAYER * 18 * EMB, 256), 256, 0, stream>>>(ge1, ge2, E12all);
    wsplit_gin_kernel<<<cdiv(NLAYER * (NP1 * KP1 + NP2 * NP1), 256), 256, 0, stream>>>(
        w1, w2, wplanes);
    wsplit_kernel<<<cdiv(NP2 * KP1, 256), 256, 0, stream>>>(pw1, EMB, EMB, pw1t_hi, pw1t_lo, KP1, NP2);
    wsplit_kernel<<<cdiv(NP2 * NP2, 256), 256, 0, stream>>>(pw2, EMB, EMB, pw2t_hi, pw2t_lo, NP2, NP2);
    wsplit_kernel<<<cdiv(NP2 * NP2, 256), 256, 0, stream>>>(gw,  EMB, EMB, gwt_hi,  gwt_lo,  NP2, NP2);
    launch_zero(statsAll, (size_t)NLAYER * 2 * EMB, stream);

    // ---- embed: initial state (f32, ld SLD) into bufA ----
    embed_kernel<<<gElemsN, 256, 0, stream>>>(x, atom1, atom2, (float*)bufA, N);

    // ---- 5 GIN layers with ping-pong buffers ----
    char* ping = bufA;   // state f32 at loop top
    char* pong = bufB;
    for (int l = 0; l < NLAYER; ++l) {
        gin_gather_il<<<cdiv(N, 4), 256, 0, stream>>>(
            (const float*)ping,
            scaleAll + (size_t)(l > 0 ? l - 1 : 0) * EMB,
            shiftAll + (size_t)(l > 0 ? l - 1 : 0) * EMB, (l > 0) ? 1 : 0,
            csr_off, csr_eid, ei, ea, E12all + (size_t)l * 18 * EMB,
            (uint_t*)pong, N);
        uint_t* til = (uint_t*)ping;    // hidden scratch in dead ping
        for (int c0 = 0; c0 < N; c0 += CH) {
            int rows = min(CH, N - c0);
            int Mt = cdiv(rows, 128);
            gemm_il<<<dim3(NP1 / 128, Mt), 256, 0, stream>>>(
                (const uint_t*)pong + (size_t)c0 * SLD, SLD, rows, EMB,
                w1t_hi[l], w1t_lo[l], KP1,
                b1 + (size_t)l * EMB2, KP1, EMB2,
                nullptr, 0, til, NP1, 1, 1, nullptr);
            gemm_il<<<dim3(NP2 / 128, Mt), 256, 0, stream>>>(
                til, NP1, rows, NP1,
                w2t_hi[l], w2t_lo[l], NP1,
                b2 + (size_t)l * EMB, NP1, EMB,
                (float*)pong + (size_t)c0 * SLD, SLD, nullptr, 0, 0, 0,
                statsAll + (size_t)l * 2 * EMB);
        }
        bn_finalize_kernel<<<cdiv(EMB, 256), 256, 0, stream>>>(
            statsAll + (size_t)l * 2 * EMB, bng + (size_t)l * EMB, bnb + (size_t)l * EMB,
            scaleAll + (size_t)l * EMB, shiftAll + (size_t)l * EMB, 1.f / (float)N);
        char* tmp = ping; ping = pong; pong = tmp;
    }
    // final state in ping; pong free arena

    // ---- P-phase arena in pong (~104 MB <= 116 MB) ----
    char* ap = pong;
    auto acv = [&](size_t bytes) -> char* {
        char* r = ap;
        ap += (bytes + 255) & ~(size_t)255;
        return r;
    };
    float*  outp     = (float*)acv((size_t)P * EMB * 4);
    float*  f0       = (float*)acv((size_t)P * EMB * 4);
    float*  xw       = (float*)acv((size_t)P * EMB * 4);
    float*  pred     = (float*)acv((size_t)P * EMB * 4);
    float*  f1       = (float*)acv((size_t)P * EMB * 4);
    uint_t* pooledIl = (uint_t*)acv((size_t)PM * KP1 * 4);
    uint_t* tmpIl    = (uint_t*)acv((size_t)PM * NP2 * 4);
    uint_t* outIl    = (uint_t*)acv((size_t)PM * NP2 * 4);

    // pool -> packed pooled (analytic BN of last layer)
    pool_gather_il<<<cdiv(P, 4), 256, 0, stream>>>(
        (const float*)ping, scaleAll + (size_t)(NLAYER - 1) * EMB,
        shiftAll + (size_t)(NLAYER - 1) * EMB, poff, pooledIl, P);

    // ---- projector (MFMA) ----
    const int MtP = PM / 128;
    gemm_il<<<dim3(NP2 / 128, MtP), 256, 0, stream>>>(
        pooledIl, KP1, P, EMB, pw1t_hi, pw1t_lo, KP1,
        pb1, KP1, EMB, nullptr, 0, tmpIl, NP2, 1, 1, nullptr);
    gemm_il<<<dim3(NP2 / 128, MtP), 256, 0, stream>>>(
        tmpIl, NP2, P, NP2, pw2t_hi, pw2t_lo, NP2,
        pb2, NP2, EMB, outp, EMB, outIl, NP2, 0, 2, nullptr);
    normalize_rows_kernel<<<cdiv(P, 4), 256, 0, stream>>>(outp, f0, P);

    // ---- GCN predictor ----
    gemm_il<<<dim3(NP2 / 128, MtP), 256, 0, stream>>>(
        outIl, NP2, P, NP2, gwt_hi, gwt_lo, NP2,
        gb, NP2, EMB, xw, EMB, nullptr, 0, 0, 0, nullptr);
    launch_zero(deg, (size_t)P, stream);
    launch_zero(pred, (size_t)P * EMB, stream);
    deg_kernel<<<cdiv(2 * FE, 256), 256, 0, stream>>>(fei, deg, FE);
    gcn_scatter_kernel<<<cdiv(2 * FE, 4), 256, 0, stream>>>(
        xw, fei, dea, gcne1, gcne2, deg, pred, FE);
    normalize_rows_kernel<<<cdiv(P, 4), 256, 0, stream>>>(pred, f1, P);

    // ---- classifier ----
    classifier_kernel<<<cdiv(2 * P, 4), 256, 0, stream>>>(f0, f1, clw, clb, outF, P);
}

// Round 11
// 3380.398 us; speedup vs baseline: 1.0853x; 1.0853x over previous
//
#include <hip/hip_runtime.h>
#include <cstdint>
#include <cstddef>

#define EMB 300
#define EMB2 600
#define NLAYER 5
#define SLD 304     // state/agg row stride (300 -> 304, 1216B rows)
#define KP1 320     // padded K for GEMM1 (300 -> 320, zeros injected in-register)
#define NP1 640     // GEMM1 out width / GEMM2 K (600 -> 640)
#define NP2 384     // 300 -> 3*128 col-tile cover
#define SCAN_B 256
#define W1SZ ((size_t)NP1 * KP1 * 2)     // 409600 B, 256-aligned
#define W2SZ ((size_t)NP2 * NP1 * 2)     // 491520 B, 256-aligned
#define LSTRIDE (2 * W1SZ + 2 * W2SZ)    // per-layer weight-plane block

typedef short bf16x8 __attribute__((ext_vector_type(8)));
typedef float f32x4 __attribute__((ext_vector_type(4)));
typedef unsigned int u32x4 __attribute__((ext_vector_type(4)));
typedef unsigned short ushort_t;
typedef unsigned int uint_t;

static inline int cdiv(int a, int b) { return (a + b - 1) / b; }

__device__ inline ushort_t f2bf(float v) {
    unsigned u = __float_as_uint(v);
    u += 0x7fffu + ((u >> 16) & 1u);
    return (ushort_t)(u >> 16);
}
__device__ inline float bf2f(ushort_t h) { return __uint_as_float(((unsigned)h) << 16); }

// pack fp32 -> interleaved word: hi bf16 in [15:0], lo bf16 in [31:16]
__device__ inline uint_t packbf(float v) {
    ushort_t h = f2bf(v);
    ushort_t l = f2bf(v - bf2f(h));
    return (uint_t)h | ((uint_t)l << 16);
}
__device__ inline u32x4 pack4(f32x4 v) {
    u32x4 w;
    #pragma unroll
    for (int j = 0; j < 4; ++j) w[j] = packbf(v[j]);
    return w;
}

__device__ inline f32x4 bnrelu4(f32x4 v, f32x4 s, f32x4 h, bool use_bn) {
    if (!use_bn) return v;
    f32x4 r;
    #pragma unroll
    for (int j = 0; j < 4; ++j) r[j] = fmaxf(fmaf(v[j], s[j], h[j]), 0.f);
    return r;
}

// ---------------- zero fill ----------------
__global__ __launch_bounds__(256) void zero_kernel(float* __restrict__ p, size_t n)
{
    size_t i = (size_t)blockIdx.x * blockDim.x + threadIdx.x;
    size_t stride = (size_t)gridDim.x * blockDim.x;
    for (; i < n; i += stride) p[i] = 0.f;
}
static inline void launch_zero(float* p, size_t n, hipStream_t s)
{
    int g = (int)((n + 255) / 256);
    if (g > 2048) g = 2048;
    zero_kernel<<<g, 256, 0, s>>>(p, n);
}
__global__ __launch_bounds__(256) void izero_kernel(int* __restrict__ p, int n)
{
    int i = blockIdx.x * 256 + threadIdx.x;
    if (i < n) p[i] = 0;
}

// ---------------- embed (ld = SLD) ----------------
__global__ __launch_bounds__(256) void embed_kernel(
    const int* __restrict__ x, const float* __restrict__ a1,
    const float* __restrict__ a2, float* __restrict__ h, int N)
{
    int idx = blockIdx.x * blockDim.x + threadIdx.x;
    if (idx >= N * EMB) return;
    int row = idx / EMB, col = idx % EMB;
    h[(size_t)row * SLD + col] = a1[x[2 * row] * EMB + col] + a2[x[2 * row + 1] * EMB + col];
}

// ---------------- CSR build ----------------
__global__ __launch_bounds__(256) void count_kernel(
    const int* __restrict__ dst, int* __restrict__ cnt, int E)
{
    int e = blockIdx.x * 256 + threadIdx.x;
    if (e < E) atomicAdd(&cnt[dst[e]], 1);
}

__global__ __launch_bounds__(SCAN_B) void scan_block_kernel(
    const int* __restrict__ in, int* __restrict__ out, int* __restrict__ bsum, int n)
{
    __shared__ int s[SCAN_B];
    int t = threadIdx.x, i = blockIdx.x * SCAN_B + t;
    int v = (i < n) ? in[i] : 0;
    s[t] = v; __syncthreads();
    for (int o = 1; o < SCAN_B; o <<= 1) {
        int xv = (t >= o) ? s[t - o] : 0;
        __syncthreads();
        s[t] += xv;
        __syncthreads();
    }
    if (i < n) out[i] = s[t] - v;
    if (t == SCAN_B - 1) bsum[blockIdx.x] = s[t];
}

__global__ __launch_bounds__(512) void scan_partials_kernel(
    const int* __restrict__ bsum, int* __restrict__ bbase, int nb)
{
    __shared__ int s[512];
    int t = threadIdx.x;
    int v = (t < nb) ? bsum[t] : 0;
    s[t] = v; __syncthreads();
    for (int o = 1; o < 512; o <<= 1) {
        int xv = (t >= o) ? s[t - o] : 0;
        __syncthreads();
        s[t] += xv;
        __syncthreads();
    }
    if (t < nb) bbase[t] = s[t] - v;
}

__global__ __launch_bounds__(256) void scan_add_kernel(
    int* __restrict__ off, const int* __restrict__ bbase, int n, int total)
{
    int i = blockIdx.x * 256 + threadIdx.x;
    if (i < n) off[i] += bbase[i / SCAN_B];
    if (i == 0) off[n] = total;
}

__global__ __launch_bounds__(256) void fill_kernel(
    const int* __restrict__ dst, const int* __restrict__ off,
    int* __restrict__ cursor, int* __restrict__ eid, int E)
{
    int e = blockIdx.x * 256 + threadIdx.x;
    if (e >= E) return;
    int d = dst[e];
    int p = atomicAdd(&cursor[d], 1);
    eid[off[d] + p] = e;
}

// ---------------- fragment range offsets (frag_batch sorted) ----------------
__global__ __launch_bounds__(256) void poff_kernel(
    const int* __restrict__ fb, int* __restrict__ poff, int N, int P)
{
    int i = blockIdx.x * 256 + threadIdx.x;
    if (i >= N) return;
    int b = fb[i];
    if (i == 0) { for (int q = 0; q <= b; ++q) poff[q] = 0; }
    else { int a = fb[i - 1]; for (int q = a + 1; q <= b; ++q) poff[q] = i; }
    if (i == N - 1) { for (int q = b + 1; q <= P; ++q) poff[q] = N; }
}

// ---------------- edge-emb combos ----------------
__global__ __launch_bounds__(256) void e12all_kernel(
    const float* __restrict__ ge1, const float* __restrict__ ge2,
    float* __restrict__ E12all)
{
    int idx = blockIdx.x * 256 + threadIdx.x;
    if (idx >= NLAYER * 18 * EMB) return;
    int l = idx / (18 * EMB);
    int rem = idx - l * 18 * EMB;
    int cmb = rem / EMB, c = rem - cmb * EMB;
    E12all[idx] = ge1[(size_t)l * 6 * EMB + (cmb / 3) * EMB + c]
                + ge2[(size_t)l * 3 * EMB + (cmb % 3) * EMB + c];
}

// ---------------- BN finalize ----------------
__global__ __launch_bounds__(256) void bn_finalize_kernel(
    const float* __restrict__ stats, const float* __restrict__ g,
    const float* __restrict__ b, float* __restrict__ scale,
    float* __restrict__ shift, float invN)
{
    int c = blockIdx.x * 256 + threadIdx.x;
    if (c >= EMB) return;
    float mu = stats[c] * invN;
    float var = fmaf(-mu, mu, stats[EMB + c] * invN);
    float s = rsqrtf(var + 1e-5f) * g[c];
    scale[c] = s;
    shift[c] = fmaf(-mu, s, b[c]);
}

// ---------------- GIN gather (R9-proven form): state(f32, ld SLD) -> packed agg (u32, ld SLD) ----------------
__global__ __launch_bounds__(256) void gin_gather_il(
    const float* __restrict__ hin, const float* __restrict__ scale,
    const float* __restrict__ shift, int use_bn,
    const int* __restrict__ off, const int* __restrict__ eid,
    const int* __restrict__ src, const int* __restrict__ ea,
    const float* __restrict__ E12, uint_t* __restrict__ Yil, int N)
{
    int node = (blockIdx.x * blockDim.x + threadIdx.x) >> 6;
    int lane = threadIdx.x & 63;
    if (node >= N) return;
    const bool tl = lane < 11;            // cols 256..299
    const int c0 = lane * 4, c1 = 256 + lane * 4;
    f32x4 sc0 = {1,1,1,1}, sh0 = {0,0,0,0}, sc1 = {1,1,1,1}, sh1 = {0,0,0,0};
    if (use_bn) {
        sc0 = *(const f32x4*)(scale + c0); sh0 = *(const f32x4*)(shift + c0);
        if (tl) { sc1 = *(const f32x4*)(scale + c1); sh1 = *(const f32x4*)(shift + c1); }
    }
    const float* selfrow = E12 + 12 * EMB;   // (a0=4, a1=0)
    f32x4 a0, a1 = {0,0,0,0};
    {
        const float* hr = hin + (size_t)node * SLD;
        a0 = bnrelu4(*(const f32x4*)(hr + c0), sc0, sh0, use_bn) + *(const f32x4*)(selfrow + c0);
        if (tl) a1 = bnrelu4(*(const f32x4*)(hr + c1), sc1, sh1, use_bn) + *(const f32x4*)(selfrow + c1);
    }
    int j0 = off[node], j1 = off[node + 1];
    int s = 0, cmb = 0;
    if (j0 < j1) { int e = eid[j0]; s = src[e]; cmb = ea[2 * e] * 3 + ea[2 * e + 1]; }
    for (int j = j0; j < j1; ++j) {
        int sn = 0, cn = 0;
        if (j + 1 < j1) {            // prefetch next edge header chain
            int en = eid[j + 1];
            sn = src[en];
            cn = ea[2 * en] * 3 + ea[2 * en + 1];
        }
        const float* hs = hin + (size_t)s * SLD;
        const float* er = E12 + (size_t)cmb * EMB;
        a0 += bnrelu4(*(const f32x4*)(hs + c0), sc0, sh0, use_bn) + *(const f32x4*)(er + c0);
        if (tl) a1 += bnrelu4(*(const f32x4*)(hs + c1), sc1, sh1, use_bn) + *(const f32x4*)(er + c1);
        s = sn; cmb = cn;
    }
    uint_t* pw = Yil + (size_t)node * SLD;
    __builtin_nontemporal_store(pack4(a0), (u32x4*)(pw + c0));
    if (tl) __builtin_nontemporal_store(pack4(a1), (u32x4*)(pw + c1));  // cols 300..303 never read
}

// ---------------- bf16x3 MFMA GEMM: interleaved u32 A, planar B ----------------
// out_mode: 0 = fp32 masked (+stats); 1 = packed full-tile (zero pad); 2 = both.
__global__ __launch_bounds__(256) void gemm_il(
    const uint_t* __restrict__ Ail, int lda, int Mvalid, int Kvalid,
    const ushort_t* __restrict__ Bhi, const ushort_t* __restrict__ Blo, int ldb,
    const float* __restrict__ bias, int Kpad, int Nvalid,
    float* __restrict__ Cf, int ldcf,
    uint_t* __restrict__ Cil, int ldcs,
    int relu, int out_mode, float* __restrict__ stats)
{
    __shared__ ushort_t As[2][128][40];   // 40-pad: frag b128 reads bank-balanced
    __shared__ ushort_t Bs[2][128][40];
    __shared__ float cred[128][2];
    const int tid = threadIdx.x;
    const int lane = tid & 63, wid = tid >> 6;
    const int wr = wid >> 1, wc = wid & 1;
    const int lr = lane & 15, ko = (lane >> 4) * 8;

    // bijective XCD swizzle (m204)
    int gx = gridDim.x;
    int nwg = gx * gridDim.y;
    int flat = blockIdx.y * gx + blockIdx.x;
    if (nwg >= 8) {
        int q = nwg >> 3, r = nwg & 7, xc = flat & 7, s = flat >> 3;
        flat = (xc < r ? xc * (q + 1) : r * (q + 1) + (xc - r) * q) + s;
    }
    const int row0 = (flat / gx) * 128, col0 = (flat % gx) * 128;

    const int srow = tid >> 1;
    const int sc = (tid & 1) * 16;

    const bool arow_ok = (row0 + srow) < Mvalid;
    const uint_t* pA = Ail + (size_t)(row0 + srow) * lda + sc;
    const ushort_t* pBhi = Bhi + (size_t)(col0 + srow) * ldb + sc;
    const ushort_t* pBlo = Blo + (size_t)(col0 + srow) * ldb + sc;
    const u32x4 z4 = {0u, 0u, 0u, 0u};

    f32x4 acc[4][4] = {};
    u32x4 LA[4];
    bf16x8 rB0, rB1, rB2, rB3;

    #pragma unroll
    for (int q = 0; q < 4; ++q) {
        int kc = sc + q * 4;
        LA[q] = (arow_ok && kc < Kvalid) ? *(const u32x4*)(pA + q * 4) : z4;
    }
    rB0 = *(const bf16x8*)(pBhi);     rB1 = *(const bf16x8*)(pBhi + 8);
    rB2 = *(const bf16x8*)(pBlo);     rB3 = *(const bf16x8*)(pBlo + 8);

    for (int k0 = 0; k0 < Kpad; k0 += 32) {
        uint_t hw[8], lw[8];
        #pragma unroll
        for (int i = 0; i < 8; ++i) {
            uint_t w0 = LA[(2 * i) >> 2][(2 * i) & 3];
            uint_t w1 = LA[(2 * i + 1) >> 2][(2 * i + 1) & 3];
            hw[i] = (w0 & 0xFFFFu) | (w1 << 16);
            lw[i] = (w0 >> 16) | (w1 & 0xFFFF0000u);
        }
        *(u32x4*)&As[0][srow][sc]     = (u32x4){hw[0], hw[1], hw[2], hw[3]};
        *(u32x4*)&As[0][srow][sc + 8] = (u32x4){hw[4], hw[5], hw[6], hw[7]};
        *(u32x4*)&As[1][srow][sc]     = (u32x4){lw[0], lw[1], lw[2], lw[3]};
        *(u32x4*)&As[1][srow][sc + 8] = (u32x4){lw[4], lw[5], lw[6], lw[7]};
        *(bf16x8*)&Bs[0][srow][sc]     = rB0;
        *(bf16x8*)&Bs[0][srow][sc + 8] = rB1;
        *(bf16x8*)&Bs[1][srow][sc]     = rB2;
        *(bf16x8*)&Bs[1][srow][sc + 8] = rB3;
        __syncthreads();
        if (k0 + 32 < Kpad) {
            int kn = k0 + 32;
            #pragma unroll
            for (int q = 0; q < 4; ++q) {
                int kc = kn + sc + q * 4;
                LA[q] = (arow_ok && kc < Kvalid) ? *(const u32x4*)(pA + kn + q * 4) : z4;
            }
            rB0 = *(const bf16x8*)(pBhi + kn);     rB1 = *(const bf16x8*)(pBhi + kn + 8);
            rB2 = *(const bf16x8*)(pBlo + kn);     rB3 = *(const bf16x8*)(pBlo + kn + 8);
        }
        bf16x8 afh[4], afl[4], bfh[4], bfl[4];
        #pragma unroll
        for (int f = 0; f < 4; ++f) {
            int ar = wr * 64 + f * 16 + lr;
            afh[f] = *(const bf16x8*)&As[0][ar][ko];
            afl[f] = *(const bf16x8*)&As[1][ar][ko];
            int bc = wc * 64 + f * 16 + lr;
            bfh[f] = *(const bf16x8*)&Bs[0][bc][ko];
            bfl[f] = *(const bf16x8*)&Bs[1][bc][ko];
        }
        #pragma unroll
        for (int f = 0; f < 4; ++f)
            #pragma unroll
            for (int g = 0; g < 4; ++g) {
                acc[f][g] = __builtin_amdgcn_mfma_f32_16x16x32_bf16(afh[f], bfh[g], acc[f][g], 0, 0, 0);
                acc[f][g] = __builtin_amdgcn_mfma_f32_16x16x32_bf16(afh[f], bfl[g], acc[f][g], 0, 0, 0);
                acc[f][g] = __builtin_amdgcn_mfma_f32_16x16x32_bf16(afl[f], bfh[g], acc[f][g], 0, 0, 0);
            }
        __syncthreads();
    }

    // epilogue: C/D mapping col=lane&15, row=(lane>>4)*4+reg  [m89-verified]
    float ts[4] = {0.f, 0.f, 0.f, 0.f}, ts2[4] = {0.f, 0.f, 0.f, 0.f};
    #pragma unroll
    for (int f = 0; f < 4; ++f) {
        int grb = row0 + wr * 64 + f * 16 + (lane >> 4) * 4;
        #pragma unroll
        for (int g = 0; g < 4; ++g) {
            int gc = col0 + wc * 64 + g * 16 + lr;
            float bv = (gc < Nvalid) ? bias[gc] : 0.f;
            #pragma unroll
            for (int j = 0; j < 4; ++j) {
                int gr = grb + j;
                float v = acc[f][g][j] + bv;
                if (relu) v = fmaxf(v, 0.f);
                if (out_mode != 1) {              // fp32 masked (+stats)
                    if (gr < Mvalid && gc < Nvalid) {
                        Cf[(size_t)gr * ldcf + gc] = v;
                        if (stats) {
                            ts[g] += v;
                            ts2[g] = fmaf(v, v, ts2[g]);
                        }
                    }
                }
                if (out_mode >= 1) {              // packed full-tile, zero pad
                    float vp = (gc < Nvalid) ? v : 0.f;
                    Cil[(size_t)gr * ldcs + gc] = packbf(vp);
                }
            }
        }
    }
    if (stats && out_mode != 1) {
        ((float*)cred)[tid] = 0.f;
        __syncthreads();
        #pragma unroll
        for (int g = 0; g < 4; ++g) {
            int cidx = wc * 64 + g * 16 + lr;
            atomicAdd(&cred[cidx][0], ts[g]);
            atomicAdd(&cred[cidx][1], ts2[g]);
        }
        __syncthreads();
        if (tid < 128) {
            int gc = col0 + tid;
            if (gc < Nvalid) {
                atomicAdd(&stats[gc], cred[tid][0]);
                atomicAdd(&stats[EMB + gc], cred[tid][1]);
            }
        }
    }
}

// ---------------- batched GIN weight split (all 5 layers, one launch) ----------------
__global__ __launch_bounds__(256) void wsplit_gin_kernel(
    const float* __restrict__ w1, const float* __restrict__ w2, char* __restrict__ base)
{
    const int perLayer = NP1 * KP1 + NP2 * NP1;
    int idx = blockIdx.x * 256 + threadIdx.x;
    if (idx >= NLAYER * perLayer) return;
    int l = idx / perLayer;
    int r = idx - l * perLayer;
    char* lb = base + (size_t)l * LSTRIDE;
    if (r < NP1 * KP1) {                  // w1t: [NP1][KP1] from w1[l][EMB][EMB2]
        int n = r / KP1, k = r - n * KP1;
        float v = (n < EMB2 && k < EMB) ? w1[(size_t)l * EMB * EMB2 + (size_t)k * EMB2 + n] : 0.f;
        ushort_t h = f2bf(v);
        ((ushort_t*)lb)[r] = h;
        ((ushort_t*)(lb + W1SZ))[r] = f2bf(v - bf2f(h));
    } else {                              // w2t: [NP2][NP1] from w2[l][EMB2][EMB]
        r -= NP1 * KP1;
        int n = r / NP1, k = r - n * NP1;
        float v = (n < EMB && k < EMB2) ? w2[(size_t)l * EMB2 * EMB + (size_t)k * EMB + n] : 0.f;
        ushort_t h = f2bf(v);
        ((ushort_t*)(lb + 2 * W1SZ))[r] = h;
        ((ushort_t*)(lb + 2 * W1SZ + W2SZ))[r] = f2bf(v - bf2f(h));
    }
}

// ---------------- weight transpose + split (P-phase, planar hi/lo) ----------------
__global__ __launch_bounds__(256) void wsplit_kernel(
    const float* __restrict__ W, int K, int Nc,
    ushort_t* __restrict__ hi, ushort_t* __restrict__ lo, int Kpad, int Npad)
{
    int idx = blockIdx.x * 256 + threadIdx.x;
    if (idx >= Npad * Kpad) return;
    int n = idx / Kpad, k = idx - n * Kpad;
    float v = (n < Nc && k < K) ? W[(size_t)k * Nc + n] : 0.f;
    ushort_t h = f2bf(v);
    hi[idx] = h;
    lo[idx] = f2bf(v - bf2f(h));
}

// ---------------- pool: contiguous ranges + analytic BN -> PACKED pooled (ld KP1) ----------------
__global__ __launch_bounds__(256) void pool_gather_il(
    const float* __restrict__ hin, const float* __restrict__ scale,
    const float* __restrict__ shift, const int* __restrict__ poff,
    uint_t* __restrict__ pooledIl, int P)
{
    int p = (blockIdx.x * blockDim.x + threadIdx.x) >> 6;
    int lane = threadIdx.x & 63;
    if (p >= P) return;
    const bool tl = lane < 11;
    const int c0 = lane * 4, c1 = 256 + lane * 4;
    int r0 = poff[p], r1 = poff[p + 1];
    f32x4 s0 = {0,0,0,0}, s1 = {0,0,0,0};
    for (int r = r0; r < r1; ++r) {
        const float* hr = hin + (size_t)r * SLD;
        s0 += *(const f32x4*)(hr + c0);
        if (tl) s1 += *(const f32x4*)(hr + c1);
    }
    float cntf = (float)(r1 - r0);
    float inv = 1.f / fmaxf(cntf, 1.f);
    f32x4 sc0 = *(const f32x4*)(scale + c0), sh0 = *(const f32x4*)(shift + c0);
    f32x4 o0;
    #pragma unroll
    for (int j = 0; j < 4; ++j) o0[j] = fmaf(s0[j], sc0[j], cntf * sh0[j]) * inv;
    uint_t* pr = pooledIl + (size_t)p * KP1;
    *(u32x4*)(pr + c0) = pack4(o0);
    if (tl) {
        f32x4 sc1 = *(const f32x4*)(scale + c1), sh1 = *(const f32x4*)(shift + c1);
        f32x4 o1;
        #pragma unroll
        for (int j = 0; j < 4; ++j) o1[j] = fmaf(s1[j], sc1[j], cntf * sh1[j]) * inv;
        *(u32x4*)(pr + c1) = pack4(o1);   // cols 300..319 masked by Kvalid in gemm
    }
}

// ---------------- row L2 normalize ----------------
__global__ __launch_bounds__(256) void normalize_rows_kernel(
    const float* __restrict__ X, float* __restrict__ Y, int M)
{
    int wv = (blockIdx.x * blockDim.x + threadIdx.x) >> 6;
    int lane = threadIdx.x & 63;
    if (wv >= M) return;
    const float* x = X + (size_t)wv * EMB;
    float ss = 0.f;
    for (int c = lane; c < EMB; c += 64) { float v = x[c]; ss = fmaf(v, v, ss); }
    #pragma unroll
    for (int o = 32; o > 0; o >>= 1) ss += __shfl_xor(ss, o, 64);
    float inv = 1.f / fmaxf(sqrtf(ss), 1e-12f);
    float* y = Y + (size_t)wv * EMB;
    for (int c = lane; c < EMB; c += 64) y[c] = x[c] * inv;
}

// ---------------- GCN ----------------
__global__ __launch_bounds__(256) void deg_kernel(
    const int* __restrict__ fei, float* __restrict__ deg, int FE)
{
    int i = blockIdx.x * blockDim.x + threadIdx.x;
    if (i < 2 * FE) atomicAdd(&deg[fei[i]], 1.f);
}

__global__ __launch_bounds__(256) void gcn_scatter_kernel(
    const float* __restrict__ xw, const int* __restrict__ fei,
    const int* __restrict__ dea, const float* __restrict__ e1,
    const float* __restrict__ e2, const float* __restrict__ deg,
    float* __restrict__ pred, int FE)
{
    int i = (blockIdx.x * blockDim.x + threadIdx.x) >> 6;
    int lane = threadIdx.x & 63;
    if (i >= 2 * FE) return;
    int u = fei[i];
    int v = (i < FE) ? fei[i + FE] : fei[i - FE];
    int er = (i < FE) ? i : i - FE;
    int a0 = dea[2 * er], a1 = dea[2 * er + 1];
    float du = deg[u], dv = deg[v];
    float su = du > 0.f ? rsqrtf(fmaxf(du, 1.f)) : 0.f;
    float sv = dv > 0.f ? rsqrtf(fmaxf(dv, 1.f)) : 0.f;
    float nr = su * sv;
    const float* xu = xw + (size_t)u * EMB;
    const float* t1 = e1 + (size_t)a0 * EMB;
    const float* t2 = e2 + (size_t)a1 * EMB;
    float* pv = pred + (size_t)v * EMB;
    for (int c = lane; c < EMB; c += 64)
        atomicAdd(&pv[c], nr * (xu[c] + t1[c] + t2[c]));
}

// ---------------- classifier ----------------
__global__ __launch_bounds__(256) void classifier_kernel(
    const float* __restrict__ f0, const float* __restrict__ f1,
    const float* __restrict__ w, const float* __restrict__ b,
    float* __restrict__ out, int P)
{
    int q = (blockIdx.x * blockDim.x + threadIdx.x) >> 6;
    int lane = threadIdx.x & 63;
    if (q >= 2 * P) return;
    int i = (q < P) ? q : q - P;
    int j = (q < P) ? i : (i == 0 ? P - 1 : i - 1);
    const float* a = f0 + (size_t)i * EMB;
    const float* c = f1 + (size_t)j * EMB;
    float s = 0.f;
    for (int k = lane; k < EMB; k += 64) s = fmaf(fmaxf(a[k], c[k]), w[k], s);
    #pragma unroll
    for (int o = 32; o > 0; o >>= 1) s += __shfl_xor(s, o, 64);
    if (lane == 0) out[q] = s + b[0];
}

extern "C" void kernel_launch(void* const* d_in, const int* in_sizes, int n_in,
                              void* d_out, int out_size, void* d_ws, size_t ws_size,
                              hipStream_t stream)
{
    const int*   x     = (const int*)d_in[0];
    const int*   ei    = (const int*)d_in[1];
    const int*   ea    = (const int*)d_in[2];
    const int*   fb    = (const int*)d_in[3];
    const int*   fei   = (const int*)d_in[4];
    const int*   dea   = (const int*)d_in[5];
    const float* atom1 = (const float*)d_in[7];
    const float* atom2 = (const float*)d_in[8];
    const float* ge1   = (const float*)d_in[9];
    const float* ge2   = (const float*)d_in[10];
    const float* w1    = (const float*)d_in[11];
    const float* b1    = (const float*)d_in[12];
    const float* w2    = (const float*)d_in[13];
    const float* b2    = (const float*)d_in[14];
    const float* bng   = (const float*)d_in[15];
    const float* bnb   = (const float*)d_in[16];
    const float* pw1   = (const float*)d_in[17];
    const float* pb1   = (const float*)d_in[18];
    const float* pw2   = (const float*)d_in[19];
    const float* pb2   = (const float*)d_in[20];
    const float* gw    = (const float*)d_in[21];
    const float* gb    = (const float*)d_in[22];
    const float* gcne1 = (const float*)d_in[23];
    const float* gcne2 = (const float*)d_in[24];
    const float* clw   = (const float*)d_in[25];
    const float* clb   = (const float*)d_in[26];
    (void)n_in; (void)ws_size;

    const int N  = in_sizes[0] / 2;
    const int E  = in_sizes[1] / 2;
    const int FE = in_sizes[4] / 2;
    const int P  = out_size / 2;
    const int Mfull = cdiv(N, 128) * 128;
    const int PM = cdiv(P, 128) * 128;
    float* outF = (float*)d_out;

    // ---- workspace carve: TWO ping-pong buffers + small stuff (~257 MB) ----
    char* wp = (char*)d_ws;
    auto carve = [&](size_t bytes) -> char* {
        char* r = wp;
        wp += (bytes + 255) & ~(size_t)255;
        return r;
    };
    const size_t bufElems = (size_t)Mfull * SLD;      // 4B each
    char* bufA = carve(bufElems * 4);
    char* bufB = carve(bufElems * 4);
    float* statsAll = (float*)carve((size_t)NLAYER * 2 * EMB * 4);
    float* scaleAll = (float*)carve((size_t)NLAYER * EMB * 4);
    float* shiftAll = (float*)carve((size_t)NLAYER * EMB * 4);
    float* E12all   = (float*)carve((size_t)NLAYER * 18 * EMB * 4);
    float* deg      = (float*)carve((size_t)P * 4);
    int* poff    = (int*)carve((size_t)(P + 1) * 4);
    int* cnt_i   = (int*)carve((size_t)N * 4);
    int* csr_off = (int*)carve((size_t)(N + 1) * 4);
    int* cursor  = (int*)carve((size_t)N * 4);
    int* csr_eid = (int*)carve((size_t)E * 4);
    int* bsum    = (int*)carve(512 * 4);
    int* bbase   = (int*)carve(512 * 4);
    // GIN weight planes: contiguous [w1hi|w1lo|w2hi|w2lo] per layer
    char* wplanes = carve((size_t)NLAYER * LSTRIDE);
    ushort_t* w1t_hi[NLAYER]; ushort_t* w1t_lo[NLAYER];
    ushort_t* w2t_hi[NLAYER]; ushort_t* w2t_lo[NLAYER];
    for (int l = 0; l < NLAYER; ++l) {
        char* lb = wplanes + (size_t)l * LSTRIDE;
        w1t_hi[l] = (ushort_t*)lb;
        w1t_lo[l] = (ushort_t*)(lb + W1SZ);
        w2t_hi[l] = (ushort_t*)(lb + 2 * W1SZ);
        w2t_lo[l] = (ushort_t*)(lb + 2 * W1SZ + W2SZ);
    }
    // P-phase weights: pw1t [NP2][KP1]; pw2t,gwt [NP2][NP2]
    ushort_t* pw1t_hi = (ushort_t*)carve((size_t)NP2 * KP1 * 2);
    ushort_t* pw1t_lo = (ushort_t*)carve((size_t)NP2 * KP1 * 2);
    ushort_t* pw2t_hi = (ushort_t*)carve((size_t)NP2 * NP2 * 2);
    ushort_t* pw2t_lo = (ushort_t*)carve((size_t)NP2 * NP2 * 2);
    ushort_t* gwt_hi  = (ushort_t*)carve((size_t)NP2 * NP2 * 2);
    ushort_t* gwt_lo  = (ushort_t*)carve((size_t)NP2 * NP2 * 2);

    // chunking: hidden scratch [CH][NP1] u32 lives in the DEAD ping buffer
    int chCap = (int)((bufElems * 4) / ((size_t)NP1 * 4));
    chCap &= ~127;
    int nChunks = cdiv(Mfull, chCap);
    int CH = cdiv(Mfull / 128, nChunks) * 128;

    const int gElemsN = cdiv(N * EMB, 256);
    const int NB = cdiv(N, SCAN_B);

    // ---- one-time per call ----
    izero_kernel<<<cdiv(N, 256), 256, 0, stream>>>(cnt_i, N);
    count_kernel<<<cdiv(E, 256), 256, 0, stream>>>(ei + E, cnt_i, E);
    scan_block_kernel<<<NB, SCAN_B, 0, stream>>>(cnt_i, csr_off, bsum, N);
    scan_partials_kernel<<<1, 512, 0, stream>>>(bsum, bbase, NB);
    scan_add_kernel<<<cdiv(N, 256), 256, 0, stream>>>(csr_off, bbase, N, E);
    izero_kernel<<<cdiv(N, 256), 256, 0, stream>>>(cursor, N);
    fill_kernel<<<cdiv(E, 256), 256, 0, stream>>>(ei + E, csr_off, cursor, csr_eid, E);
    poff_kernel<<<cdiv(N, 256), 256, 0, stream>>>(fb, poff, N, P);
    e12all_kernel<<<cdiv(NLAYER * 18 * EMB, 256), 256, 0, stream>>>(ge1, ge2, E12all);
    wsplit_gin_kernel<<<cdiv(NLAYER * (NP1 * KP1 + NP2 * NP1), 256), 256, 0, stream>>>(
        w1, w2, wplanes);
    wsplit_kernel<<<cdiv(NP2 * KP1, 256), 256, 0, stream>>>(pw1, EMB, EMB, pw1t_hi, pw1t_lo, KP1, NP2);
    wsplit_kernel<<<cdiv(NP2 * NP2, 256), 256, 0, stream>>>(pw2, EMB, EMB, pw2t_hi, pw2t_lo, NP2, NP2);
    wsplit_kernel<<<cdiv(NP2 * NP2, 256), 256, 0, stream>>>(gw,  EMB, EMB, gwt_hi,  gwt_lo,  NP2, NP2);
    launch_zero(statsAll, (size_t)NLAYER * 2 * EMB, stream);

    // ---- embed: initial state (f32, ld SLD) into bufA ----
    embed_kernel<<<gElemsN, 256, 0, stream>>>(x, atom1, atom2, (float*)bufA, N);

    // ---- 5 GIN layers with ping-pong buffers ----
    char* ping = bufA;   // state f32 at loop top
    char* pong = bufB;
    for (int l = 0; l < NLAYER; ++l) {
        gin_gather_il<<<cdiv(N, 4), 256, 0, stream>>>(
            (const float*)ping,
            scaleAll + (size_t)(l > 0 ? l - 1 : 0) * EMB,
            shiftAll + (size_t)(l > 0 ? l - 1 : 0) * EMB, (l > 0) ? 1 : 0,
            csr_off, csr_eid, ei, ea, E12all + (size_t)l * 18 * EMB,
            (uint_t*)pong, N);
        uint_t* til = (uint_t*)ping;    // hidden scratch in dead ping
        for (int c0 = 0; c0 < N; c0 += CH) {
            int rows = min(CH, N - c0);
            int Mt = cdiv(rows, 128);
            gemm_il<<<dim3(NP1 / 128, Mt), 256, 0, stream>>>(
                (const uint_t*)pong + (size_t)c0 * SLD, SLD, rows, EMB,
                w1t_hi[l], w1t_lo[l], KP1,
                b1 + (size_t)l * EMB2, KP1, EMB2,
                nullptr, 0, til, NP1, 1, 1, nullptr);
            gemm_il<<<dim3(NP2 / 128, Mt), 256, 0, stream>>>(
                til, NP1, rows, NP1,
                w2t_hi[l], w2t_lo[l], NP1,
                b2 + (size_t)l * EMB, NP1, EMB,
                (float*)pong + (size_t)c0 * SLD, SLD, nullptr, 0, 0, 0,
                statsAll + (size_t)l * 2 * EMB);
        }
        bn_finalize_kernel<<<cdiv(EMB, 256), 256, 0, stream>>>(
            statsAll + (size_t)l * 2 * EMB, bng + (size_t)l * EMB, bnb + (size_t)l * EMB,
            scaleAll + (size_t)l * EMB, shiftAll + (size_t)l * EMB, 1.f / (float)N);
        char* tmp = ping; ping = pong; pong = tmp;
    }
    // final state in ping; pong free arena

    // ---- P-phase arena in pong (~104 MB <= 116 MB) ----
    char* ap = pong;
    auto acv = [&](size_t bytes) -> char* {
        char* r = ap;
        ap += (bytes + 255) & ~(size_t)255;
        return r;
    };
    float*  outp     = (float*)acv((size_t)P * EMB * 4);
    float*  f0       = (float*)acv((size_t)P * EMB * 4);
    float*  xw       = (float*)acv((size_t)P * EMB * 4);
    float*  pred     = (float*)acv((size_t)P * EMB * 4);
    float*  f1       = (float*)acv((size_t)P * EMB * 4);
    uint_t* pooledIl = (uint_t*)acv((size_t)PM * KP1 * 4);
    uint_t* tmpIl    = (uint_t*)acv((size_t)PM * NP2 * 4);
    uint_t* outIl    = (uint_t*)acv((size_t)PM * NP2 * 4);

    // pool -> packed pooled (analytic BN of last layer)
    pool_gather_il<<<cdiv(P, 4), 256, 0, stream>>>(
        (const float*)ping, scaleAll + (size_t)(NLAYER - 1) * EMB,
        shiftAll + (size_t)(NLAYER - 1) * EMB, poff, pooledIl, P);

    // ---- projector (MFMA) ----
    const int MtP = PM / 128;
    gemm_il<<<dim3(NP2 / 128, MtP), 256, 0, stream>>>(
        pooledIl, KP1, P, EMB, pw1t_hi, pw1t_lo, KP1,
        pb1, KP1, EMB, nullptr, 0, tmpIl, NP2, 1, 1, nullptr);
    gemm_il<<<dim3(NP2 / 128, MtP), 256, 0, stream>>>(
        tmpIl, NP2, P, NP2, pw2t_hi, pw2t_lo, NP2,
        pb2, NP2, EMB, outp, EMB, outIl, NP2, 0, 2, nullptr);
    normalize_rows_kernel<<<cdiv(P, 4), 256, 0, stream>>>(outp, f0, P);

    // ---- GCN predictor ----
    gemm_il<<<dim3(NP2 / 128, MtP), 256, 0, stream>>>(
        outIl, NP2, P, NP2, gwt_hi, gwt_lo, NP2,
        gb, NP2, EMB, xw, EMB, nullptr, 0, 0, 0, nullptr);
    launch_zero(deg, (size_t)P, stream);
    launch_zero(pred, (size_t)P * EMB, stream);
    deg_kernel<<<cdiv(2 * FE, 256), 256, 0, stream>>>(fei, deg, FE);
    gcn_scatter_kernel<<<cdiv(2 * FE, 4), 256, 0, stream>>>(
        xw, fei, dea, gcne1, gcne2, deg, pred, FE);
    normalize_rows_kernel<<<cdiv(P, 4), 256, 0, stream>>>(pred, f1, P);

    // ---- classifier ----
    classifier_kernel<<<cdiv(2 * P, 4), 256, 0, stream>>>(f0, f1, clw, clb, outF, P);
}

// Round 12
// 3245.795 us; speedup vs baseline: 1.1304x; 1.0415x over previous
//
#include <hip/hip_runtime.h>
#include <cstdint>
#include <cstddef>

#define EMB 300
#define EMB2 600
#define NLAYER 5
#define SLD 304     // state/agg row stride (300 -> 304, 1216B rows)
#define KP1 320     // padded K for GEMM1 (300 -> 320, zeros injected in-register)
#define NP1 640     // GEMM1 out width / GEMM2 K (600 -> 640)
#define NP2 384     // 300 -> 3*128 col-tile cover
#define SCAN_B 256
#define W1SZ ((size_t)NP1 * KP1 * 2)     // 409600 B, 256-aligned
#define W2SZ ((size_t)NP2 * NP1 * 2)     // 491520 B, 256-aligned
#define LSTRIDE (2 * W1SZ + 2 * W2SZ)    // per-layer weight-plane block

typedef short bf16x8 __attribute__((ext_vector_type(8)));
typedef float f32x4 __attribute__((ext_vector_type(4)));
typedef unsigned int u32x4 __attribute__((ext_vector_type(4)));
typedef unsigned short ushort_t;
typedef unsigned int uint_t;

static inline int cdiv(int a, int b) { return (a + b - 1) / b; }

__device__ inline ushort_t f2bf(float v) {
    unsigned u = __float_as_uint(v);
    u += 0x7fffu + ((u >> 16) & 1u);
    return (ushort_t)(u >> 16);
}
__device__ inline float bf2f(ushort_t h) { return __uint_as_float(((unsigned)h) << 16); }

// pack fp32 -> interleaved word: hi bf16 in [15:0], lo bf16 in [31:16]
__device__ inline uint_t packbf(float v) {
    ushort_t h = f2bf(v);
    ushort_t l = f2bf(v - bf2f(h));
    return (uint_t)h | ((uint_t)l << 16);
}
__device__ inline u32x4 pack4(f32x4 v) {
    u32x4 w;
    #pragma unroll
    for (int j = 0; j < 4; ++j) w[j] = packbf(v[j]);
    return w;
}

__device__ inline f32x4 bnrelu4(f32x4 v, f32x4 s, f32x4 h, bool use_bn) {
    if (!use_bn) return v;
    f32x4 r;
    #pragma unroll
    for (int j = 0; j < 4; ++j) r[j] = fmaxf(fmaf(v[j], s[j], h[j]), 0.f);
    return r;
}

// ---------------- zero fill ----------------
__global__ __launch_bounds__(256) void zero_kernel(float* __restrict__ p, size_t n)
{
    size_t i = (size_t)blockIdx.x * blockDim.x + threadIdx.x;
    size_t stride = (size_t)gridDim.x * blockDim.x;
    for (; i < n; i += stride) p[i] = 0.f;
}
static inline void launch_zero(float* p, size_t n, hipStream_t s)
{
    int g = (int)((n + 255) / 256);
    if (g > 2048) g = 2048;
    zero_kernel<<<g, 256, 0, s>>>(p, n);
}
__global__ __launch_bounds__(256) void izero_kernel(int* __restrict__ p, int n)
{
    int i = blockIdx.x * 256 + threadIdx.x;
    if (i < n) p[i] = 0;
}

// ---------------- embed (ld = SLD) ----------------
__global__ __launch_bounds__(256) void embed_kernel(
    const int* __restrict__ x, const float* __restrict__ a1,
    const float* __restrict__ a2, float* __restrict__ h, int N)
{
    int idx = blockIdx.x * blockDim.x + threadIdx.x;
    if (idx >= N * EMB) return;
    int row = idx / EMB, col = idx % EMB;
    h[(size_t)row * SLD + col] = a1[x[2 * row] * EMB + col] + a2[x[2 * row + 1] * EMB + col];
}

// ---------------- CSR build ----------------
__global__ __launch_bounds__(256) void count_kernel(
    const int* __restrict__ dst, int* __restrict__ cnt, int E)
{
    int e = blockIdx.x * 256 + threadIdx.x;
    if (e < E) atomicAdd(&cnt[dst[e]], 1);
}

__global__ __launch_bounds__(SCAN_B) void scan_block_kernel(
    const int* __restrict__ in, int* __restrict__ out, int* __restrict__ bsum, int n)
{
    __shared__ int s[SCAN_B];
    int t = threadIdx.x, i = blockIdx.x * SCAN_B + t;
    int v = (i < n) ? in[i] : 0;
    s[t] = v; __syncthreads();
    for (int o = 1; o < SCAN_B; o <<= 1) {
        int xv = (t >= o) ? s[t - o] : 0;
        __syncthreads();
        s[t] += xv;
        __syncthreads();
    }
    if (i < n) out[i] = s[t] - v;
    if (t == SCAN_B - 1) bsum[blockIdx.x] = s[t];
}

__global__ __launch_bounds__(512) void scan_partials_kernel(
    const int* __restrict__ bsum, int* __restrict__ bbase, int nb)
{
    __shared__ int s[512];
    int t = threadIdx.x;
    int v = (t < nb) ? bsum[t] : 0;
    s[t] = v; __syncthreads();
    for (int o = 1; o < 512; o <<= 1) {
        int xv = (t >= o) ? s[t - o] : 0;
        __syncthreads();
        s[t] += xv;
        __syncthreads();
    }
    if (t < nb) bbase[t] = s[t] - v;
}

__global__ __launch_bounds__(256) void scan_add_kernel(
    int* __restrict__ off, const int* __restrict__ bbase, int n, int total)
{
    int i = blockIdx.x * 256 + threadIdx.x;
    if (i < n) off[i] += bbase[i / SCAN_B];
    if (i == 0) off[n] = total;
}

// fill PACKED headers: pk = (src << 5) | cmb  (src < 2^17, cmb < 18)
__global__ __launch_bounds__(256) void fill_kernel(
    const int* __restrict__ src, const int* __restrict__ dst,
    const int* __restrict__ ea, const int* __restrict__ off,
    int* __restrict__ cursor, uint_t* __restrict__ pks, int E)
{
    int e = blockIdx.x * 256 + threadIdx.x;
    if (e >= E) return;
    int d = dst[e];
    int p = atomicAdd(&cursor[d], 1);
    uint_t pk = ((uint_t)src[e] << 5) | (uint_t)(ea[2 * e] * 3 + ea[2 * e + 1]);
    pks[off[d] + p] = pk;
}

// ---------------- fragment range offsets (frag_batch sorted) ----------------
__global__ __launch_bounds__(256) void poff_kernel(
    const int* __restrict__ fb, int* __restrict__ poff, int N, int P)
{
    int i = blockIdx.x * 256 + threadIdx.x;
    if (i >= N) return;
    int b = fb[i];
    if (i == 0) { for (int q = 0; q <= b; ++q) poff[q] = 0; }
    else { int a = fb[i - 1]; for (int q = a + 1; q <= b; ++q) poff[q] = i; }
    if (i == N - 1) { for (int q = b + 1; q <= P; ++q) poff[q] = N; }
}

// ---------------- edge-emb combos ----------------
__global__ __launch_bounds__(256) void e12all_kernel(
    const float* __restrict__ ge1, const float* __restrict__ ge2,
    float* __restrict__ E12all)
{
    int idx = blockIdx.x * 256 + threadIdx.x;
    if (idx >= NLAYER * 18 * EMB) return;
    int l = idx / (18 * EMB);
    int rem = idx - l * 18 * EMB;
    int cmb = rem / EMB, c = rem - cmb * EMB;
    E12all[idx] = ge1[(size_t)l * 6 * EMB + (cmb / 3) * EMB + c]
                + ge2[(size_t)l * 3 * EMB + (cmb % 3) * EMB + c];
}

// ---------------- BN finalize ----------------
__global__ __launch_bounds__(256) void bn_finalize_kernel(
    const float* __restrict__ stats, const float* __restrict__ g,
    const float* __restrict__ b, float* __restrict__ scale,
    float* __restrict__ shift, float invN)
{
    int c = blockIdx.x * 256 + threadIdx.x;
    if (c >= EMB) return;
    float mu = stats[c] * invN;
    float var = fmaf(-mu, mu, stats[EMB + c] * invN);
    float s = rsqrtf(var + 1e-5f) * g[c];
    scale[c] = s;
    shift[c] = fmaf(-mu, s, b[c]);
}

// ---------------- GIN gather (packed headers): state(f32, ld SLD) -> packed agg (u32, ld SLD) ----------------
__global__ __launch_bounds__(256) void gin_gather_il(
    const float* __restrict__ hin, const float* __restrict__ scale,
    const float* __restrict__ shift, int use_bn,
    const int* __restrict__ off, const uint_t* __restrict__ pks,
    const float* __restrict__ E12, uint_t* __restrict__ Yil, int N)
{
    int node = (blockIdx.x * blockDim.x + threadIdx.x) >> 6;
    int lane = threadIdx.x & 63;
    if (node >= N) return;
    const bool tl = lane < 11;            // cols 256..299
    const int c0 = lane * 4, c1 = 256 + lane * 4;
    f32x4 sc0 = {1,1,1,1}, sh0 = {0,0,0,0}, sc1 = {1,1,1,1}, sh1 = {0,0,0,0};
    if (use_bn) {
        sc0 = *(const f32x4*)(scale + c0); sh0 = *(const f32x4*)(shift + c0);
        if (tl) { sc1 = *(const f32x4*)(scale + c1); sh1 = *(const f32x4*)(shift + c1); }
    }
    const float* selfrow = E12 + 12 * EMB;   // (a0=4, a1=0)
    f32x4 a0, a1 = {0,0,0,0};
    {
        const float* hr = hin + (size_t)node * SLD;
        a0 = bnrelu4(*(const f32x4*)(hr + c0), sc0, sh0, use_bn) + *(const f32x4*)(selfrow + c0);
        if (tl) a1 = bnrelu4(*(const f32x4*)(hr + c1), sc1, sh1, use_bn) + *(const f32x4*)(selfrow + c1);
    }
    int j0 = off[node], j1 = off[node + 1];
    uint_t pk = (j0 < j1) ? pks[j0] : 0u;
    for (int j = j0; j < j1; ++j) {
        uint_t pkn = (j + 1 < j1) ? pks[j + 1] : 0u;   // single-load prefetch
        int s = (int)(pk >> 5);
        int cmb = (int)(pk & 31u);
        const float* hs = hin + (size_t)s * SLD;
        const float* er = E12 + (size_t)cmb * EMB;
        a0 += bnrelu4(*(const f32x4*)(hs + c0), sc0, sh0, use_bn) + *(const f32x4*)(er + c0);
        if (tl) a1 += bnrelu4(*(const f32x4*)(hs + c1), sc1, sh1, use_bn) + *(const f32x4*)(er + c1);
        pk = pkn;
    }
    uint_t* pw = Yil + (size_t)node * SLD;
    __builtin_nontemporal_store(pack4(a0), (u32x4*)(pw + c0));
    if (tl) __builtin_nontemporal_store(pack4(a1), (u32x4*)(pw + c1));  // cols 300..303 never read
}

// ---------------- bf16x3 MFMA GEMM: interleaved u32 A, planar B ----------------
// out_mode: 0 = fp32 masked (+stats); 1 = packed full-tile (zero pad); 2 = both.
__global__ __launch_bounds__(256) void gemm_il(
    const uint_t* __restrict__ Ail, int lda, int Mvalid, int Kvalid,
    const ushort_t* __restrict__ Bhi, const ushort_t* __restrict__ Blo, int ldb,
    const float* __restrict__ bias, int Kpad, int Nvalid,
    float* __restrict__ Cf, int ldcf,
    uint_t* __restrict__ Cil, int ldcs,
    int relu, int out_mode, float* __restrict__ stats)
{
    __shared__ ushort_t As[2][128][40];   // 40-pad: frag b128 reads bank-balanced
    __shared__ ushort_t Bs[2][128][40];
    __shared__ float cred[128][2];
    const int tid = threadIdx.x;
    const int lane = tid & 63, wid = tid >> 6;
    const int wr = wid >> 1, wc = wid & 1;
    const int lr = lane & 15, ko = (lane >> 4) * 8;

    // bijective XCD swizzle (m204)
    int gx = gridDim.x;
    int nwg = gx * gridDim.y;
    int flat = blockIdx.y * gx + blockIdx.x;
    if (nwg >= 8) {
        int q = nwg >> 3, r = nwg & 7, xc = flat & 7, s = flat >> 3;
        flat = (xc < r ? xc * (q + 1) : r * (q + 1) + (xc - r) * q) + s;
    }
    const int row0 = (flat / gx) * 128, col0 = (flat % gx) * 128;

    const int srow = tid >> 1;
    const int sc = (tid & 1) * 16;

    const bool arow_ok = (row0 + srow) < Mvalid;
    const uint_t* pA = Ail + (size_t)(row0 + srow) * lda + sc;
    const ushort_t* pBhi = Bhi + (size_t)(col0 + srow) * ldb + sc;
    const ushort_t* pBlo = Blo + (size_t)(col0 + srow) * ldb + sc;
    const u32x4 z4 = {0u, 0u, 0u, 0u};

    f32x4 acc[4][4] = {};
    u32x4 LA[4];
    bf16x8 rB0, rB1, rB2, rB3;

    #pragma unroll
    for (int q = 0; q < 4; ++q) {
        int kc = sc + q * 4;
        LA[q] = (arow_ok && kc < Kvalid) ? *(const u32x4*)(pA + q * 4) : z4;
    }
    rB0 = *(const bf16x8*)(pBhi);     rB1 = *(const bf16x8*)(pBhi + 8);
    rB2 = *(const bf16x8*)(pBlo);     rB3 = *(const bf16x8*)(pBlo + 8);

    for (int k0 = 0; k0 < Kpad; k0 += 32) {
        uint_t hw[8], lw[8];
        #pragma unroll
        for (int i = 0; i < 8; ++i) {
            uint_t w0 = LA[(2 * i) >> 2][(2 * i) & 3];
            uint_t w1 = LA[(2 * i + 1) >> 2][(2 * i + 1) & 3];
            hw[i] = (w0 & 0xFFFFu) | (w1 << 16);
            lw[i] = (w0 >> 16) | (w1 & 0xFFFF0000u);
        }
        *(u32x4*)&As[0][srow][sc]     = (u32x4){hw[0], hw[1], hw[2], hw[3]};
        *(u32x4*)&As[0][srow][sc + 8] = (u32x4){hw[4], hw[5], hw[6], hw[7]};
        *(u32x4*)&As[1][srow][sc]     = (u32x4){lw[0], lw[1], lw[2], lw[3]};
        *(u32x4*)&As[1][srow][sc + 8] = (u32x4){lw[4], lw[5], lw[6], lw[7]};
        *(bf16x8*)&Bs[0][srow][sc]     = rB0;
        *(bf16x8*)&Bs[0][srow][sc + 8] = rB1;
        *(bf16x8*)&Bs[1][srow][sc]     = rB2;
        *(bf16x8*)&Bs[1][srow][sc + 8] = rB3;
        __syncthreads();
        if (k0 + 32 < Kpad) {
            int kn = k0 + 32;
            #pragma unroll
            for (int q = 0; q < 4; ++q) {
                int kc = kn + sc + q * 4;
                LA[q] = (arow_ok && kc < Kvalid) ? *(const u32x4*)(pA + kn + q * 4) : z4;
            }
            rB0 = *(const bf16x8*)(pBhi + kn);     rB1 = *(const bf16x8*)(pBhi + kn + 8);
            rB2 = *(const bf16x8*)(pBlo + kn);     rB3 = *(const bf16x8*)(pBlo + kn + 8);
        }
        bf16x8 afh[4], afl[4], bfh[4], bfl[4];
        #pragma unroll
        for (int f = 0; f < 4; ++f) {
            int ar = wr * 64 + f * 16 + lr;
            afh[f] = *(const bf16x8*)&As[0][ar][ko];
            afl[f] = *(const bf16x8*)&As[1][ar][ko];
            int bc = wc * 64 + f * 16 + lr;
            bfh[f] = *(const bf16x8*)&Bs[0][bc][ko];
            bfl[f] = *(const bf16x8*)&Bs[1][bc][ko];
        }
        #pragma unroll
        for (int f = 0; f < 4; ++f)
            #pragma unroll
            for (int g = 0; g < 4; ++g) {
                acc[f][g] = __builtin_amdgcn_mfma_f32_16x16x32_bf16(afh[f], bfh[g], acc[f][g], 0, 0, 0);
                acc[f][g] = __builtin_amdgcn_mfma_f32_16x16x32_bf16(afh[f], bfl[g], acc[f][g], 0, 0, 0);
                acc[f][g] = __builtin_amdgcn_mfma_f32_16x16x32_bf16(afl[f], bfh[g], acc[f][g], 0, 0, 0);
            }
        __syncthreads();
    }

    // epilogue: C/D mapping col=lane&15, row=(lane>>4)*4+reg  [m89-verified]
    float ts[4] = {0.f, 0.f, 0.f, 0.f}, ts2[4] = {0.f, 0.f, 0.f, 0.f};
    #pragma unroll
    for (int f = 0; f < 4; ++f) {
        int grb = row0 + wr * 64 + f * 16 + (lane >> 4) * 4;
        #pragma unroll
        for (int g = 0; g < 4; ++g) {
            int gc = col0 + wc * 64 + g * 16 + lr;
            float bv = (gc < Nvalid) ? bias[gc] : 0.f;
            #pragma unroll
            for (int j = 0; j < 4; ++j) {
                int gr = grb + j;
                float v = acc[f][g][j] + bv;
                if (relu) v = fmaxf(v, 0.f);
                if (out_mode != 1) {              // fp32 masked (+stats)
                    if (gr < Mvalid && gc < Nvalid) {
                        Cf[(size_t)gr * ldcf + gc] = v;
                        if (stats) {
                            ts[g] += v;
                            ts2[g] = fmaf(v, v, ts2[g]);
                        }
                    }
                }
                if (out_mode >= 1) {              // packed full-tile, zero pad
                    float vp = (gc < Nvalid) ? v : 0.f;
                    Cil[(size_t)gr * ldcs + gc] = packbf(vp);
                }
            }
        }
    }
    if (stats && out_mode != 1) {
        ((float*)cred)[tid] = 0.f;
        __syncthreads();
        #pragma unroll
        for (int g = 0; g < 4; ++g) {
            int cidx = wc * 64 + g * 16 + lr;
            atomicAdd(&cred[cidx][0], ts[g]);
            atomicAdd(&cred[cidx][1], ts2[g]);
        }
        __syncthreads();
        if (tid < 128) {
            int gc = col0 + tid;
            if (gc < Nvalid) {
                atomicAdd(&stats[gc], cred[tid][0]);
                atomicAdd(&stats[EMB + gc], cred[tid][1]);
            }
        }
    }
}

// ---------------- batched GIN weight split (all 5 layers, one launch) ----------------
__global__ __launch_bounds__(256) void wsplit_gin_kernel(
    const float* __restrict__ w1, const float* __restrict__ w2, char* __restrict__ base)
{
    const int perLayer = NP1 * KP1 + NP2 * NP1;
    int idx = blockIdx.x * 256 + threadIdx.x;
    if (idx >= NLAYER * perLayer) return;
    int l = idx / perLayer;
    int r = idx - l * perLayer;
    char* lb = base + (size_t)l * LSTRIDE;
    if (r < NP1 * KP1) {                  // w1t: [NP1][KP1] from w1[l][EMB][EMB2]
        int n = r / KP1, k = r - n * KP1;
        float v = (n < EMB2 && k < EMB) ? w1[(size_t)l * EMB * EMB2 + (size_t)k * EMB2 + n] : 0.f;
        ushort_t h = f2bf(v);
        ((ushort_t*)lb)[r] = h;
        ((ushort_t*)(lb + W1SZ))[r] = f2bf(v - bf2f(h));
    } else {                              // w2t: [NP2][NP1] from w2[l][EMB2][EMB]
        r -= NP1 * KP1;
        int n = r / NP1, k = r - n * NP1;
        float v = (n < EMB && k < EMB2) ? w2[(size_t)l * EMB2 * EMB + (size_t)k * EMB + n] : 0.f;
        ushort_t h = f2bf(v);
        ((ushort_t*)(lb + 2 * W1SZ))[r] = h;
        ((ushort_t*)(lb + 2 * W1SZ + W2SZ))[r] = f2bf(v - bf2f(h));
    }
}

// ---------------- weight transpose + split (P-phase, planar hi/lo) ----------------
__global__ __launch_bounds__(256) void wsplit_kernel(
    const float* __restrict__ W, int K, int Nc,
    ushort_t* __restrict__ hi, ushort_t* __restrict__ lo, int Kpad, int Npad)
{
    int idx = blockIdx.x * 256 + threadIdx.x;
    if (idx >= Npad * Kpad) return;
    int n = idx / Kpad, k = idx - n * Kpad;
    float v = (n < Nc && k < K) ? W[(size_t)k * Nc + n] : 0.f;
    ushort_t h = f2bf(v);
    hi[idx] = h;
    lo[idx] = f2bf(v - bf2f(h));
}

// ---------------- pool: contiguous ranges + analytic BN -> PACKED pooled (ld KP1) ----------------
__global__ __launch_bounds__(256) void pool_gather_il(
    const float* __restrict__ hin, const float* __restrict__ scale,
    const float* __restrict__ shift, const int* __restrict__ poff,
    uint_t* __restrict__ pooledIl, int P)
{
    int p = (blockIdx.x * blockDim.x + threadIdx.x) >> 6;
    int lane = threadIdx.x & 63;
    if (p >= P) return;
    const bool tl = lane < 11;
    const int c0 = lane * 4, c1 = 256 + lane * 4;
    int r0 = poff[p], r1 = poff[p + 1];
    f32x4 s0 = {0,0,0,0}, s1 = {0,0,0,0};
    for (int r = r0; r < r1; ++r) {
        const float* hr = hin + (size_t)r * SLD;
        s0 += *(const f32x4*)(hr + c0);
        if (tl) s1 += *(const f32x4*)(hr + c1);
    }
    float cntf = (float)(r1 - r0);
    float inv = 1.f / fmaxf(cntf, 1.f);
    f32x4 sc0 = *(const f32x4*)(scale + c0), sh0 = *(const f32x4*)(shift + c0);
    f32x4 o0;
    #pragma unroll
    for (int j = 0; j < 4; ++j) o0[j] = fmaf(s0[j], sc0[j], cntf * sh0[j]) * inv;
    uint_t* pr = pooledIl + (size_t)p * KP1;
    *(u32x4*)(pr + c0) = pack4(o0);
    if (tl) {
        f32x4 sc1 = *(const f32x4*)(scale + c1), sh1 = *(const f32x4*)(shift + c1);
        f32x4 o1;
        #pragma unroll
        for (int j = 0; j < 4; ++j) o1[j] = fmaf(s1[j], sc1[j], cntf * sh1[j]) * inv;
        *(u32x4*)(pr + c1) = pack4(o1);   // cols 300..319 masked by Kvalid in gemm
    }
}

// ---------------- row L2 normalize ----------------
__global__ __launch_bounds__(256) void normalize_rows_kernel(
    const float* __restrict__ X, float* __restrict__ Y, int M)
{
    int wv = (blockIdx.x * blockDim.x + threadIdx.x) >> 6;
    int lane = threadIdx.x & 63;
    if (wv >= M) return;
    const float* x = X + (size_t)wv * EMB;
    float ss = 0.f;
    for (int c = lane; c < EMB; c += 64) { float v = x[c]; ss = fmaf(v, v, ss); }
    #pragma unroll
    for (int o = 32; o > 0; o >>= 1) ss += __shfl_xor(ss, o, 64);
    float inv = 1.f / fmaxf(sqrtf(ss), 1e-12f);
    float* y = Y + (size_t)wv * EMB;
    for (int c = lane; c < EMB; c += 64) y[c] = x[c] * inv;
}

// ---------------- GCN ----------------
__global__ __launch_bounds__(256) void deg_kernel(
    const int* __restrict__ fei, float* __restrict__ deg, int FE)
{
    int i = blockIdx.x * blockDim.x + threadIdx.x;
    if (i < 2 * FE) atomicAdd(&deg[fei[i]], 1.f);
}

__global__ __launch_bounds__(256) void gcn_scatter_kernel(
    const float* __restrict__ xw, const int* __restrict__ fei,
    const int* __restrict__ dea, const float* __restrict__ e1,
    const float* __restrict__ e2, const float* __restrict__ deg,
    float* __restrict__ pred, int FE)
{
    int i = (blockIdx.x * blockDim.x + threadIdx.x) >> 6;
    int lane = threadIdx.x & 63;
    if (i >= 2 * FE) return;
    int u = fei[i];
    int v = (i < FE) ? fei[i + FE] : fei[i - FE];
    int er = (i < FE) ? i : i - FE;
    int a0 = dea[2 * er], a1 = dea[2 * er + 1];
    float du = deg[u], dv = deg[v];
    float su = du > 0.f ? rsqrtf(fmaxf(du, 1.f)) : 0.f;
    float sv = dv > 0.f ? rsqrtf(fmaxf(dv, 1.f)) : 0.f;
    float nr = su * sv;
    const float* xu = xw + (size_t)u * EMB;
    const float* t1 = e1 + (size_t)a0 * EMB;
    const float* t2 = e2 + (size_t)a1 * EMB;
    float* pv = pred + (size_t)v * EMB;
    for (int c = lane; c < EMB; c += 64)
        atomicAdd(&pv[c], nr * (xu[c] + t1[c] + t2[c]));
}

// ---------------- classifier ----------------
__global__ __launch_bounds__(256) void classifier_kernel(
    const float* __restrict__ f0, const float* __restrict__ f1,
    const float* __restrict__ w, const float* __restrict__ b,
    float* __restrict__ out, int P)
{
    int q = (blockIdx.x * blockDim.x + threadIdx.x) >> 6;
    int lane = threadIdx.x & 63;
    if (q >= 2 * P) return;
    int i = (q < P) ? q : q - P;
    int j = (q < P) ? i : (i == 0 ? P - 1 : i - 1);
    const float* a = f0 + (size_t)i * EMB;
    const float* c = f1 + (size_t)j * EMB;
    float s = 0.f;
    for (int k = lane; k < EMB; k += 64) s = fmaf(fmaxf(a[k], c[k]), w[k], s);
    #pragma unroll
    for (int o = 32; o > 0; o >>= 1) s += __shfl_xor(s, o, 64);
    if (lane == 0) out[q] = s + b[0];
}

extern "C" void kernel_launch(void* const* d_in, const int* in_sizes, int n_in,
                              void* d_out, int out_size, void* d_ws, size_t ws_size,
                              hipStream_t stream)
{
    const int*   x     = (const int*)d_in[0];
    const int*   ei    = (const int*)d_in[1];
    const int*   ea    = (const int*)d_in[2];
    const int*   fb    = (const int*)d_in[3];
    const int*   fei   = (const int*)d_in[4];
    const int*   dea   = (const int*)d_in[5];
    const float* atom1 = (const float*)d_in[7];
    const float* atom2 = (const float*)d_in[8];
    const float* ge1   = (const float*)d_in[9];
    const float* ge2   = (const float*)d_in[10];
    const float* w1    = (const float*)d_in[11];
    const float* b1    = (const float*)d_in[12];
    const float* w2    = (const float*)d_in[13];
    const float* b2    = (const float*)d_in[14];
    const float* bng   = (const float*)d_in[15];
    const float* bnb   = (const float*)d_in[16];
    const float* pw1   = (const float*)d_in[17];
    const float* pb1   = (const float*)d_in[18];
    const float* pw2   = (const float*)d_in[19];
    const float* pb2   = (const float*)d_in[20];
    const float* gw    = (const float*)d_in[21];
    const float* gb    = (const float*)d_in[22];
    const float* gcne1 = (const float*)d_in[23];
    const float* gcne2 = (const float*)d_in[24];
    const float* clw   = (const float*)d_in[25];
    const float* clb   = (const float*)d_in[26];
    (void)n_in; (void)ws_size;

    const int N  = in_sizes[0] / 2;
    const int E  = in_sizes[1] / 2;
    const int FE = in_sizes[4] / 2;
    const int P  = out_size / 2;
    const int Mfull = cdiv(N, 128) * 128;
    const int PM = cdiv(P, 128) * 128;
    float* outF = (float*)d_out;

    // ---- workspace carve: TWO ping-pong buffers + small stuff (~257 MB) ----
    char* wp = (char*)d_ws;
    auto carve = [&](size_t bytes) -> char* {
        char* r = wp;
        wp += (bytes + 255) & ~(size_t)255;
        return r;
    };
    const size_t bufElems = (size_t)Mfull * SLD;      // 4B each
    char* bufA = carve(bufElems * 4);
    char* bufB = carve(bufElems * 4);
    float* statsAll = (float*)carve((size_t)NLAYER * 2 * EMB * 4);
    float* scaleAll = (float*)carve((size_t)NLAYER * EMB * 4);
    float* shiftAll = (float*)carve((size_t)NLAYER * EMB * 4);
    float* E12all   = (float*)carve((size_t)NLAYER * 18 * EMB * 4);
    float* deg      = (float*)carve((size_t)P * 4);
    int* poff    = (int*)carve((size_t)(P + 1) * 4);
    int* cnt_i   = (int*)carve((size_t)N * 4);
    int* csr_off = (int*)carve((size_t)(N + 1) * 4);
    int* cursor  = (int*)carve((size_t)N * 4);
    uint_t* csr_pk = (uint_t*)carve((size_t)E * 4);
    int* bsum    = (int*)carve(512 * 4);
    int* bbase   = (int*)carve(512 * 4);
    // GIN weight planes: contiguous [w1hi|w1lo|w2hi|w2lo] per layer
    char* wplanes = carve((size_t)NLAYER * LSTRIDE);
    ushort_t* w1t_hi[NLAYER]; ushort_t* w1t_lo[NLAYER];
    ushort_t* w2t_hi[NLAYER]; ushort_t* w2t_lo[NLAYER];
    for (int l = 0; l < NLAYER; ++l) {
        char* lb = wplanes + (size_t)l * LSTRIDE;
        w1t_hi[l] = (ushort_t*)lb;
        w1t_lo[l] = (ushort_t*)(lb + W1SZ);
        w2t_hi[l] = (ushort_t*)(lb + 2 * W1SZ);
        w2t_lo[l] = (ushort_t*)(lb + 2 * W1SZ + W2SZ);
    }
    // P-phase weights: pw1t [NP2][KP1]; pw2t,gwt [NP2][NP2]
    ushort_t* pw1t_hi = (ushort_t*)carve((size_t)NP2 * KP1 * 2);
    ushort_t* pw1t_lo = (ushort_t*)carve((size_t)NP2 * KP1 * 2);
    ushort_t* pw2t_hi = (ushort_t*)carve((size_t)NP2 * NP2 * 2);
    ushort_t* pw2t_lo = (ushort_t*)carve((size_t)NP2 * NP2 * 2);
    ushort_t* gwt_hi  = (ushort_t*)carve((size_t)NP2 * NP2 * 2);
    ushort_t* gwt_lo  = (ushort_t*)carve((size_t)NP2 * NP2 * 2);

    // chunking: hidden scratch [CH][NP1] u32 lives in the DEAD ping buffer
    int chCap = (int)((bufElems * 4) / ((size_t)NP1 * 4));
    chCap &= ~127;
    int nChunks = cdiv(Mfull, chCap);
    int CH = cdiv(Mfull / 128, nChunks) * 128;

    const int gElemsN = cdiv(N * EMB, 256);
    const int NB = cdiv(N, SCAN_B);

    // ---- one-time per call ----
    izero_kernel<<<cdiv(N, 256), 256, 0, stream>>>(cnt_i, N);
    count_kernel<<<cdiv(E, 256), 256, 0, stream>>>(ei + E, cnt_i, E);
    scan_block_kernel<<<NB, SCAN_B, 0, stream>>>(cnt_i, csr_off, bsum, N);
    scan_partials_kernel<<<1, 512, 0, stream>>>(bsum, bbase, NB);
    scan_add_kernel<<<cdiv(N, 256), 256, 0, stream>>>(csr_off, bbase, N, E);
    izero_kernel<<<cdiv(N, 256), 256, 0, stream>>>(cursor, N);
    fill_kernel<<<cdiv(E, 256), 256, 0, stream>>>(ei, ei + E, ea, csr_off, cursor, csr_pk, E);
    poff_kernel<<<cdiv(N, 256), 256, 0, stream>>>(fb, poff, N, P);
    e12all_kernel<<<cdiv(NLAYER * 18 * EMB, 256), 256, 0, stream>>>(ge1, ge2, E12all);
    wsplit_gin_kernel<<<cdiv(NLAYER * (NP1 * KP1 + NP2 * NP1), 256), 256, 0, stream>>>(
        w1, w2, wplanes);
    wsplit_kernel<<<cdiv(NP2 * KP1, 256), 256, 0, stream>>>(pw1, EMB, EMB, pw1t_hi, pw1t_lo, KP1, NP2);
    wsplit_kernel<<<cdiv(NP2 * NP2, 256), 256, 0, stream>>>(pw2, EMB, EMB, pw2t_hi, pw2t_lo, NP2, NP2);
    wsplit_kernel<<<cdiv(NP2 * NP2, 256), 256, 0, stream>>>(gw,  EMB, EMB, gwt_hi,  gwt_lo,  NP2, NP2);
    launch_zero(statsAll, (size_t)NLAYER * 2 * EMB, stream);

    // ---- embed: initial state (f32, ld SLD) into bufA ----
    embed_kernel<<<gElemsN, 256, 0, stream>>>(x, atom1, atom2, (float*)bufA, N);

    // ---- 5 GIN layers with ping-pong buffers ----
    char* ping = bufA;   // state f32 at loop top
    char* pong = bufB;
    for (int l = 0; l < NLAYER; ++l) {
        gin_gather_il<<<cdiv(N, 4), 256, 0, stream>>>(
            (const float*)ping,
            scaleAll + (size_t)(l > 0 ? l - 1 : 0) * EMB,
            shiftAll + (size_t)(l > 0 ? l - 1 : 0) * EMB, (l > 0) ? 1 : 0,
            csr_off, csr_pk, E12all + (size_t)l * 18 * EMB,
            (uint_t*)pong, N);
        uint_t* til = (uint_t*)ping;    // hidden scratch in dead ping
        for (int c0 = 0; c0 < N; c0 += CH) {
            int rows = min(CH, N - c0);
            int Mt = cdiv(rows, 128);
            gemm_il<<<dim3(NP1 / 128, Mt), 256, 0, stream>>>(
                (const uint_t*)pong + (size_t)c0 * SLD, SLD, rows, EMB,
                w1t_hi[l], w1t_lo[l], KP1,
                b1 + (size_t)l * EMB2, KP1, EMB2,
                nullptr, 0, til, NP1, 1, 1, nullptr);
            gemm_il<<<dim3(NP2 / 128, Mt), 256, 0, stream>>>(
                til, NP1, rows, NP1,
                w2t_hi[l], w2t_lo[l], NP1,
                b2 + (size_t)l * EMB, NP1, EMB,
                (float*)pong + (size_t)c0 * SLD, SLD, nullptr, 0, 0, 0,
                statsAll + (size_t)l * 2 * EMB);
        }
        bn_finalize_kernel<<<cdiv(EMB, 256), 256, 0, stream>>>(
            statsAll + (size_t)l * 2 * EMB, bng + (size_t)l * EMB, bnb + (size_t)l * EMB,
            scaleAll + (size_t)l * EMB, shiftAll + (size_t)l * EMB, 1.f / (float)N);
        char* tmp = ping; ping = pong; pong = tmp;
    }
    // final state in ping; pong free arena

    // ---- P-phase arena in pong (~104 MB <= 116 MB) ----
    char* ap = pong;
    auto acv = [&](size_t bytes) -> char* {
        char* r = ap;
        ap += (bytes + 255) & ~(size_t)255;
        return r;
    };
    float*  outp     = (float*)acv((size_t)P * EMB * 4);
    float*  f0       = (float*)acv((size_t)P * EMB * 4);
    float*  xw       = (float*)acv((size_t)P * EMB * 4);
    float*  pred     = (float*)acv((size_t)P * EMB * 4);
    float*  f1       = (float*)acv((size_t)P * EMB * 4);
    uint_t* pooledIl = (uint_t*)acv((size_t)PM * KP1 * 4);
    uint_t* tmpIl    = (uint_t*)acv((size_t)PM * NP2 * 4);
    uint_t* outIl    = (uint_t*)acv((size_t)PM * NP2 * 4);

    // pool -> packed pooled (analytic BN of last layer)
    pool_gather_il<<<cdiv(P, 4), 256, 0, stream>>>(
        (const float*)ping, scaleAll + (size_t)(NLAYER - 1) * EMB,
        shiftAll + (size_t)(NLAYER - 1) * EMB, poff, pooledIl, P);

    // ---- projector (MFMA) ----
    const int MtP = PM / 128;
    gemm_il<<<dim3(NP2 / 128, MtP), 256, 0, stream>>>(
        pooledIl, KP1, P, EMB, pw1t_hi, pw1t_lo, KP1,
        pb1, KP1, EMB, nullptr, 0, tmpIl, NP2, 1, 1, nullptr);
    gemm_il<<<dim3(NP2 / 128, MtP), 256, 0, stream>>>(
        tmpIl, NP2, P, NP2, pw2t_hi, pw2t_lo, NP2,
        pb2, NP2, EMB, outp, EMB, outIl, NP2, 0, 2, nullptr);
    normalize_rows_kernel<<<cdiv(P, 4), 256, 0, stream>>>(outp, f0, P);

    // ---- GCN predictor ----
    gemm_il<<<dim3(NP2 / 128, MtP), 256, 0, stream>>>(
        outIl, NP2, P, NP2, gwt_hi, gwt_lo, NP2,
        gb, NP2, EMB, xw, EMB, nullptr, 0, 0, 0, nullptr);
    launch_zero(deg, (size_t)P, stream);
    launch_zero(pred, (size_t)P * EMB, stream);
    deg_kernel<<<cdiv(2 * FE, 256), 256, 0, stream>>>(fei, deg, FE);
    gcn_scatter_kernel<<<cdiv(2 * FE, 4), 256, 0, stream>>>(
        xw, fei, dea, gcne1, gcne2, deg, pred, FE);
    normalize_rows_kernel<<<cdiv(P, 4), 256, 0, stream>>>(pred, f1, P);

    // ---- classifier ----
    classifier_kernel<<<cdiv(2 * P, 4), 256, 0, stream>>>(f0, f1, clw, clb, outF, P);
}